// Round 1
// baseline (2033.517 us; speedup 1.0000x reference)
//
#include <hip/hip_runtime.h>

#define DM 128
#define NH 8
#define HD 16
#define DFF 512

// ---------------------------------------------------------------------------
// Tiled fp32 GEMM: C[M,Ncols] = A[M,K] @ B[K,Ncols]  (+bias +prelu +residual)
// 64x64 tile, 256 threads, 4x4 outputs/thread, K-step 16 via LDS.
// ---------------------------------------------------------------------------
__global__ __launch_bounds__(256) void gemm_f32(
    const float* __restrict__ A, const float* __restrict__ B,
    float* __restrict__ C, int M, int Ncols, int K,
    const float* __restrict__ bias,      // [Ncols] or nullptr
    const float* __restrict__ prelu_a,   // scalar ptr or nullptr
    const float* __restrict__ residual)  // [M,Ncols] or nullptr
{
    __shared__ float As[16][64 + 1];
    __shared__ float Bs[16][64];

    const int tid = threadIdx.x;
    const int bm = blockIdx.y * 64;
    const int bn = blockIdx.x * 64;
    const int tx = tid & 15;   // col group
    const int ty = tid >> 4;   // row group (0..15)

    float acc[4][4];
#pragma unroll
    for (int i = 0; i < 4; ++i)
#pragma unroll
        for (int j = 0; j < 4; ++j) acc[i][j] = 0.0f;

    const int lkA = tid & 15;       // k for A loads
    const int lmA = tid >> 4;       // row base for A loads
    const int lnB = tid & 63;       // col for B loads
    const int lkB = tid >> 6;       // k base for B loads

    for (int kk = 0; kk < K; kk += 16) {
#pragma unroll
        for (int p = 0; p < 4; ++p) {
            int m = lmA + p * 16;
            int row = bm + m;
            As[lkA][m] = (row < M) ? A[(size_t)row * K + kk + lkA] : 0.0f;
        }
#pragma unroll
        for (int p = 0; p < 4; ++p) {
            int k = lkB + p * 4;
            Bs[k][lnB] = B[(size_t)(kk + k) * Ncols + bn + lnB];
        }
        __syncthreads();
#pragma unroll
        for (int k = 0; k < 16; ++k) {
            float a[4], b[4];
#pragma unroll
            for (int i = 0; i < 4; ++i) a[i] = As[k][ty + i * 16];
#pragma unroll
            for (int j = 0; j < 4; ++j) b[j] = Bs[k][tx + j * 16];
#pragma unroll
            for (int i = 0; i < 4; ++i)
#pragma unroll
                for (int j = 0; j < 4; ++j) acc[i][j] = fmaf(a[i], b[j], acc[i][j]);
        }
        __syncthreads();
    }

    float aslope = prelu_a ? *prelu_a : 0.0f;
#pragma unroll
    for (int i = 0; i < 4; ++i) {
        int row = bm + ty + i * 16;
        if (row >= M) continue;
#pragma unroll
        for (int j = 0; j < 4; ++j) {
            int col = bn + tx + j * 16;
            float v = acc[i][j];
            if (bias) v += bias[col];
            if (prelu_a) v = (v >= 0.0f) ? v : aslope * v;
            if (residual) v += residual[(size_t)row * Ncols + col];
            C[(size_t)row * Ncols + col] = v;
        }
    }
}

// el[n,h] = sum_d z[n,h,d]*attn_l[h,d] ; er likewise
__global__ void el_er_kernel(const float* __restrict__ z,
                             const float* __restrict__ al,
                             const float* __restrict__ ar,
                             float* __restrict__ el, float* __restrict__ er, int N)
{
    int idx = blockIdx.x * blockDim.x + threadIdx.x;
    if (idx >= N * NH) return;
    int n = idx >> 3, h = idx & 7;
    const float* zp = z + (size_t)n * DM + h * HD;
    const float* alp = al + h * HD;
    const float* arp = ar + h * HD;
    float sl = 0.0f, sr = 0.0f;
#pragma unroll
    for (int d = 0; d < HD; ++d) {
        float zv = zp[d];
        sl = fmaf(zv, alp[d], sl);
        sr = fmaf(zv, arp[d], sr);
    }
    el[idx] = sl;
    er[idx] = sr;
}

// per (edge, head): w = exp(leaky_relu(el[src]+er[dst])); denom[dst,h] += w
__global__ void edge_attn_kernel(const int* __restrict__ src, const int* __restrict__ dst,
                                 const float* __restrict__ el, const float* __restrict__ er,
                                 float* __restrict__ wedge, float* __restrict__ denom, int E)
{
    int idx = blockIdx.x * blockDim.x + threadIdx.x;
    if (idx >= E * NH) return;
    int e = idx >> 3, h = idx & 7;
    int s = src[e], t = dst[e];
    float v = el[s * NH + h] + er[t * NH + h];
    v = (v >= 0.0f) ? v : 0.2f * v;
    float w = expf(v);   // segment_max cancels exactly in softmax; |v| is O(few)
    wedge[idx] = w;
    atomicAdd(&denom[t * NH + h], w);
}

// per (edge, channel): agg[dst,c] += w[e,h] * z[src,c]
__global__ void edge_agg_kernel(const int* __restrict__ src, const int* __restrict__ dst,
                                const float* __restrict__ z, const float* __restrict__ wedge,
                                float* __restrict__ agg, int E)
{
    int idx = blockIdx.x * blockDim.x + threadIdx.x;
    if (idx >= E * DM) return;
    int e = idx >> 7, c = idx & 127, h = c >> 4;
    int s = src[e], t = dst[e];
    float w = wedge[e * NH + h];
    atomicAdd(&agg[(size_t)t * DM + c], w * z[(size_t)s * DM + c]);
}

// out = prelu(agg/denom + conv_bias, a_conv)
__global__ void conv_prelu_kernel(const float* __restrict__ agg, const float* __restrict__ denom,
                                  const float* __restrict__ cb, const float* __restrict__ a_conv,
                                  float* __restrict__ outp, int N)
{
    int idx = blockIdx.x * blockDim.x + threadIdx.x;
    if (idx >= N * DM) return;
    int n = idx >> 7, c = idx & 127, h = c >> 4;
    float dn = fmaxf(denom[n * NH + h], 1e-9f);
    float v = agg[idx] / dn + cb[c];
    float a = *a_conv;
    outp[idx] = (v >= 0.0f) ? v : a * v;
}

// one wave per row of 128
__global__ __launch_bounds__(256) void layernorm_kernel(
    const float* __restrict__ in, float* __restrict__ out,
    const float* __restrict__ scale, const float* __restrict__ bias, int M)
{
    int wave = threadIdx.x >> 6;
    int lane = threadIdx.x & 63;
    int row = blockIdx.x * 4 + wave;
    if (row >= M) return;
    const float* r = in + (size_t)row * DM;
    float v0 = r[lane], v1 = r[lane + 64];
    float s = v0 + v1;
    float ss = v0 * v0 + v1 * v1;
#pragma unroll
    for (int off = 32; off > 0; off >>= 1) {
        s += __shfl_xor(s, off, 64);
        ss += __shfl_xor(ss, off, 64);
    }
    float mean = s * (1.0f / 128.0f);
    float var = ss * (1.0f / 128.0f) - mean * mean;
    float rstd = rsqrtf(var + 1e-5f);
    float* o = out + (size_t)row * DM;
    o[lane]      = (v0 - mean) * rstd * scale[lane]      + bias[lane];
    o[lane + 64] = (v1 - mean) * rstd * scale[lane + 64] + bias[lane + 64];
}

extern "C" void kernel_launch(void* const* d_in, const int* in_sizes, int n_in,
                              void* d_out, int out_size, void* d_ws, size_t ws_size,
                              hipStream_t stream)
{
    const float* in_feats = (const float*)d_in[0];
    const int*   src      = (const int*)d_in[1];
    const int*   dst      = (const int*)d_in[2];
    const float* W        = (const float*)d_in[3];
    const float* attn_l   = (const float*)d_in[4];
    const float* attn_r   = (const float*)d_in[5];
    const float* convb    = (const float*)d_in[6];
    const float* a_conv   = (const float*)d_in[7];
    const float* ln_scale = (const float*)d_in[8];
    const float* ln_bias  = (const float*)d_in[9];
    const float* W1       = (const float*)d_in[10];
    const float* b1       = (const float*)d_in[11];
    const float* W2       = (const float*)d_in[12];
    const float* b2       = (const float*)d_in[13];
    const float* a_ff     = (const float*)d_in[14];
    float* out = (float*)d_out;

    const int N = in_sizes[0] / DM;
    const int E = in_sizes[1];
    const int L = in_sizes[7];

    float* ws = (float*)d_ws;
    size_t off = 0;
    float* z     = ws + off; off += (size_t)N * DM;   // also reused as hconv
    float* el    = ws + off; off += (size_t)N * NH;
    float* er    = ws + off; off += (size_t)N * NH;
    float* denom = ws + off; off += (size_t)N * NH;
    float* agg   = ws + off; off += (size_t)N * DM;
    float* hbuf  = ws + off; off += (size_t)N * DM;
    float* hn    = ws + off; off += (size_t)N * DM;
    float* ffh   = ws + off; off += (size_t)N * DFF;
    float* wedge = ws + off; off += (size_t)E * NH;

    const int gM = (N + 63) / 64;

    for (int l = 0; l < L; ++l) {
        const float* x  = (l == 0) ? in_feats : out + (size_t)(l - 1) * N * DM;
        float*       xo = out + (size_t)l * N * DM;

        // z = x @ W[l]
        gemm_f32<<<dim3(DM / 64, gM), 256, 0, stream>>>(
            x, W + (size_t)l * DM * DM, z, N, DM, DM, nullptr, nullptr, nullptr);

        el_er_kernel<<<(N * NH + 255) / 256, 256, 0, stream>>>(
            z, attn_l + (size_t)l * NH * HD, attn_r + (size_t)l * NH * HD, el, er, N);

        hipMemsetAsync(denom, 0, (size_t)N * NH * sizeof(float), stream);
        hipMemsetAsync(agg, 0, (size_t)N * DM * sizeof(float), stream);

        edge_attn_kernel<<<(E * NH + 255) / 256, 256, 0, stream>>>(
            src, dst, el, er, wedge, denom, E);

        edge_agg_kernel<<<((size_t)E * DM + 255) / 256, 256, 0, stream>>>(
            src, dst, z, wedge, agg, E);

        // hconv (reuse z buffer)
        conv_prelu_kernel<<<(N * DM + 255) / 256, 256, 0, stream>>>(
            agg, denom, convb + (size_t)l * DM, a_conv + l, z, N);

        // h = LN(hconv) ; hn = LN(h)
        layernorm_kernel<<<(N + 3) / 4, 256, 0, stream>>>(
            z, hbuf, ln_scale + (size_t)l * DM, ln_bias + (size_t)l * DM, N);
        layernorm_kernel<<<(N + 3) / 4, 256, 0, stream>>>(
            hbuf, hn, ln_scale + (size_t)l * DM, ln_bias + (size_t)l * DM, N);

        // ffh = prelu(hn @ W1 + b1, a_ff)
        gemm_f32<<<dim3(DFF / 64, gM), 256, 0, stream>>>(
            hn, W1 + (size_t)l * DM * DFF, ffh, N, DFF, DM,
            b1 + (size_t)l * DFF, a_ff + l, nullptr);

        // xo = ffh @ W2 + b2 + h
        gemm_f32<<<dim3(DM / 64, gM), 256, 0, stream>>>(
            ffh, W2 + (size_t)l * DFF * DM, xo, N, DM, DFF,
            b2 + (size_t)l * DM, nullptr, hbuf);
    }
}

// Round 2
// 1396.345 us; speedup vs baseline: 1.4563x; 1.4563x over previous
//
#include <hip/hip_runtime.h>

#define DM 128
#define NH 8
#define HD 16
#define DFF 512

// ---------------------------------------------------------------------------
// Tiled fp32 GEMM: C[M,Ncols] = A[M,K] @ B[K,Ncols]  (+bias +prelu +residual)
// 64x64 tile, 256 threads, 4x4 outputs/thread, K-step 16 via LDS.
// ---------------------------------------------------------------------------
__global__ __launch_bounds__(256) void gemm_f32(
    const float* __restrict__ A, const float* __restrict__ B,
    float* __restrict__ C, int M, int Ncols, int K,
    const float* __restrict__ bias,      // [Ncols] or nullptr
    const float* __restrict__ prelu_a,   // scalar ptr or nullptr
    const float* __restrict__ residual)  // [M,Ncols] or nullptr
{
    __shared__ float As[16][64 + 1];
    __shared__ float Bs[16][64];

    const int tid = threadIdx.x;
    const int bm = blockIdx.y * 64;
    const int bn = blockIdx.x * 64;
    const int tx = tid & 15;   // col group
    const int ty = tid >> 4;   // row group (0..15)

    float acc[4][4];
#pragma unroll
    for (int i = 0; i < 4; ++i)
#pragma unroll
        for (int j = 0; j < 4; ++j) acc[i][j] = 0.0f;

    const int lkA = tid & 15;       // k for A loads
    const int lmA = tid >> 4;       // row base for A loads
    const int lnB = tid & 63;       // col for B loads
    const int lkB = tid >> 6;       // k base for B loads

    for (int kk = 0; kk < K; kk += 16) {
#pragma unroll
        for (int p = 0; p < 4; ++p) {
            int m = lmA + p * 16;
            int row = bm + m;
            As[lkA][m] = (row < M) ? A[(size_t)row * K + kk + lkA] : 0.0f;
        }
#pragma unroll
        for (int p = 0; p < 4; ++p) {
            int k = lkB + p * 4;
            Bs[k][lnB] = B[(size_t)(kk + k) * Ncols + bn + lnB];
        }
        __syncthreads();
#pragma unroll
        for (int k = 0; k < 16; ++k) {
            float a[4], b[4];
#pragma unroll
            for (int i = 0; i < 4; ++i) a[i] = As[k][ty + i * 16];
#pragma unroll
            for (int j = 0; j < 4; ++j) b[j] = Bs[k][tx + j * 16];
#pragma unroll
            for (int i = 0; i < 4; ++i)
#pragma unroll
                for (int j = 0; j < 4; ++j) acc[i][j] = fmaf(a[i], b[j], acc[i][j]);
        }
        __syncthreads();
    }

    float aslope = prelu_a ? *prelu_a : 0.0f;
#pragma unroll
    for (int i = 0; i < 4; ++i) {
        int row = bm + ty + i * 16;
        if (row >= M) continue;
#pragma unroll
        for (int j = 0; j < 4; ++j) {
            int col = bn + tx + j * 16;
            float v = acc[i][j];
            if (bias) v += bias[col];
            if (prelu_a) v = (v >= 0.0f) ? v : aslope * v;
            if (residual) v += residual[(size_t)row * Ncols + col];
            C[(size_t)row * Ncols + col] = v;
        }
    }
}

// el[n,h] = sum_d z[n,h,d]*attn_l[h,d] ; er likewise
__global__ void el_er_kernel(const float* __restrict__ z,
                             const float* __restrict__ al,
                             const float* __restrict__ ar,
                             float* __restrict__ el, float* __restrict__ er, int N)
{
    int idx = blockIdx.x * blockDim.x + threadIdx.x;
    if (idx >= N * NH) return;
    int n = idx >> 3, h = idx & 7;
    const float* zp = z + (size_t)n * DM + h * HD;
    const float* alp = al + h * HD;
    const float* arp = ar + h * HD;
    float sl = 0.0f, sr = 0.0f;
#pragma unroll
    for (int d = 0; d < HD; ++d) {
        float zv = zp[d];
        sl = fmaf(zv, alp[d], sl);
        sr = fmaf(zv, arp[d], sr);
    }
    el[idx] = sl;
    er[idx] = sr;
}

// ---------------- CSR build (once per launch, reused across layers) --------
__global__ void hist_kernel(const int* __restrict__ dst, int* __restrict__ deg, int E)
{
    int e = blockIdx.x * blockDim.x + threadIdx.x;
    if (e < E) atomicAdd(&deg[dst[e]], 1);
}

// block-level inclusive scan of 256 elems
__global__ void scan1_kernel(const int* __restrict__ deg, int* __restrict__ incl,
                             int* __restrict__ bsum, int N)
{
    __shared__ int sm[256];
    int i = blockIdx.x * 256 + threadIdx.x;
    int v = (i < N) ? deg[i] : 0;
    sm[threadIdx.x] = v;
    __syncthreads();
    for (int off = 1; off < 256; off <<= 1) {
        int t = (threadIdx.x >= off) ? sm[threadIdx.x - off] : 0;
        __syncthreads();
        sm[threadIdx.x] += t;
        __syncthreads();
    }
    if (i < N) incl[i] = sm[threadIdx.x];
    if (threadIdx.x == 255) bsum[blockIdx.x] = sm[255];
}

__global__ void scan2_kernel(int* __restrict__ bsum, int nb)
{
    __shared__ int sm[256];
    int v = (threadIdx.x < nb) ? bsum[threadIdx.x] : 0;
    sm[threadIdx.x] = v;
    __syncthreads();
    for (int off = 1; off < 256; off <<= 1) {
        int t = (threadIdx.x >= off) ? sm[threadIdx.x - off] : 0;
        __syncthreads();
        sm[threadIdx.x] += t;
        __syncthreads();
    }
    if (threadIdx.x < nb) bsum[threadIdx.x] = sm[threadIdx.x];
}

__global__ void scan3_kernel(const int* __restrict__ incl, const int* __restrict__ bsum,
                             int* __restrict__ row_ptr, int N)
{
    int i = blockIdx.x * 256 + threadIdx.x;
    if (i < N) {
        int off = (blockIdx.x > 0) ? bsum[blockIdx.x - 1] : 0;
        row_ptr[i + 1] = incl[i] + off;
    }
    if (i == 0) row_ptr[0] = 0;
}

__global__ void scatter_kernel(const int* __restrict__ src, const int* __restrict__ dst,
                               const int* __restrict__ row_ptr, int* __restrict__ cursor,
                               int* __restrict__ csr_src, int E)
{
    int e = blockIdx.x * blockDim.x + threadIdx.x;
    if (e >= E) return;
    int t = dst[e];
    int pos = atomicAdd(&cursor[t], 1);
    csr_src[row_ptr[t] + pos] = src[e];
}

// ---------------------------------------------------------------------------
// Fused edge-softmax + aggregate + bias + PReLU: one wave per dst node.
// Lane L handles channels L and L+64 (heads L>>4 and L>>4 + 4).
// segment_max cancels exactly in the softmax ratio; |e| is O(few) so exp is
// safe in fp32.
// ---------------------------------------------------------------------------
__global__ __launch_bounds__(256) void gat_agg_kernel(
    const int* __restrict__ row_ptr, const int* __restrict__ csr_src,
    const float* __restrict__ z, const float* __restrict__ el,
    const float* __restrict__ er, const float* __restrict__ cb,
    const float* __restrict__ a_conv, float* __restrict__ outp, int N)
{
    int wave = threadIdx.x >> 6, lane = threadIdx.x & 63;
    int t = blockIdx.x * 4 + wave;
    if (t >= N) return;
    int h0 = lane >> 4, h1 = h0 + 4;
    float er0 = er[t * NH + h0], er1 = er[t * NH + h1];
    int e0 = row_ptr[t], e1 = row_ptr[t + 1];
    float acc0 = 0.0f, acc1 = 0.0f, den0 = 0.0f, den1 = 0.0f;
    for (int e = e0; e < e1; ++e) {
        int s = csr_src[e];
        float v0 = el[s * NH + h0] + er0;
        float v1 = el[s * NH + h1] + er1;
        v0 = (v0 >= 0.0f) ? v0 : 0.2f * v0;
        v1 = (v1 >= 0.0f) ? v1 : 0.2f * v1;
        float w0 = __expf(v0), w1 = __expf(v1);
        den0 += w0; den1 += w1;
        const float* zp = z + (size_t)s * DM;
        acc0 = fmaf(w0, zp[lane], acc0);
        acc1 = fmaf(w1, zp[lane + 64], acc1);
    }
    float a = *a_conv;
    float o0 = acc0 / fmaxf(den0, 1e-9f) + cb[lane];
    float o1 = acc1 / fmaxf(den1, 1e-9f) + cb[lane + 64];
    outp[(size_t)t * DM + lane]      = (o0 >= 0.0f) ? o0 : a * o0;
    outp[(size_t)t * DM + lane + 64] = (o1 >= 0.0f) ? o1 : a * o1;
}

// Fused double-LayerNorm: h = LN(x), hn = LN(h). One wave per row of 128.
__global__ __launch_bounds__(256) void layernorm2_kernel(
    const float* __restrict__ in, float* __restrict__ h_out, float* __restrict__ hn_out,
    const float* __restrict__ scale, const float* __restrict__ bias, int M)
{
    int wave = threadIdx.x >> 6;
    int lane = threadIdx.x & 63;
    int row = blockIdx.x * 4 + wave;
    if (row >= M) return;
    const float* r = in + (size_t)row * DM;
    float sc0 = scale[lane], sc1 = scale[lane + 64];
    float bi0 = bias[lane], bi1 = bias[lane + 64];

    float v0 = r[lane], v1 = r[lane + 64];
    float s = v0 + v1, ss = v0 * v0 + v1 * v1;
#pragma unroll
    for (int off = 32; off > 0; off >>= 1) {
        s += __shfl_xor(s, off, 64);
        ss += __shfl_xor(ss, off, 64);
    }
    float mean = s * (1.0f / 128.0f);
    float var = ss * (1.0f / 128.0f) - mean * mean;
    float rstd = rsqrtf(var + 1e-5f);
    float h0 = (v0 - mean) * rstd * sc0 + bi0;
    float h1 = (v1 - mean) * rstd * sc1 + bi1;
    h_out[(size_t)row * DM + lane]      = h0;
    h_out[(size_t)row * DM + lane + 64] = h1;

    // second LN on h
    s = h0 + h1; ss = h0 * h0 + h1 * h1;
#pragma unroll
    for (int off = 32; off > 0; off >>= 1) {
        s += __shfl_xor(s, off, 64);
        ss += __shfl_xor(ss, off, 64);
    }
    mean = s * (1.0f / 128.0f);
    var = ss * (1.0f / 128.0f) - mean * mean;
    rstd = rsqrtf(var + 1e-5f);
    hn_out[(size_t)row * DM + lane]      = (h0 - mean) * rstd * sc0 + bi0;
    hn_out[(size_t)row * DM + lane + 64] = (h1 - mean) * rstd * sc1 + bi1;
}

extern "C" void kernel_launch(void* const* d_in, const int* in_sizes, int n_in,
                              void* d_out, int out_size, void* d_ws, size_t ws_size,
                              hipStream_t stream)
{
    const float* in_feats = (const float*)d_in[0];
    const int*   src      = (const int*)d_in[1];
    const int*   dst      = (const int*)d_in[2];
    const float* W        = (const float*)d_in[3];
    const float* attn_l   = (const float*)d_in[4];
    const float* attn_r   = (const float*)d_in[5];
    const float* convb    = (const float*)d_in[6];
    const float* a_conv   = (const float*)d_in[7];
    const float* ln_scale = (const float*)d_in[8];
    const float* ln_bias  = (const float*)d_in[9];
    const float* W1       = (const float*)d_in[10];
    const float* b1       = (const float*)d_in[11];
    const float* W2       = (const float*)d_in[12];
    const float* b2       = (const float*)d_in[13];
    const float* a_ff     = (const float*)d_in[14];
    float* out = (float*)d_out;

    const int N = in_sizes[0] / DM;
    const int E = in_sizes[1];
    const int L = in_sizes[7];

    char* wsb = (char*)d_ws;
    size_t off = 0;
    auto alloc = [&](size_t bytes) { char* p = wsb + off; off += (bytes + 255) & ~(size_t)255; return p; };

    float* z    = (float*)alloc((size_t)N * DM * sizeof(float));   // reused as hconv
    float* el   = (float*)alloc((size_t)N * NH * sizeof(float));
    float* er   = (float*)alloc((size_t)N * NH * sizeof(float));
    float* hbuf = (float*)alloc((size_t)N * DM * sizeof(float));
    float* hn   = (float*)alloc((size_t)N * DM * sizeof(float));
    float* ffh  = (float*)alloc((size_t)N * DFF * sizeof(float));
    int* deg     = (int*)alloc((size_t)N * sizeof(int));
    int* incl    = (int*)alloc((size_t)N * sizeof(int));
    int* bsum    = (int*)alloc(256 * sizeof(int));
    int* row_ptr = (int*)alloc((size_t)(N + 1) * sizeof(int));
    int* cursor  = (int*)alloc((size_t)N * sizeof(int));
    int* csr_src = (int*)alloc((size_t)E * sizeof(int));

    const int gM = (N + 63) / 64;
    const int nbScan = (N + 255) / 256;

    // ---- build CSR by dst (graph constant within one launch) ----
    hipMemsetAsync(deg, 0, (size_t)N * sizeof(int), stream);
    hipMemsetAsync(cursor, 0, (size_t)N * sizeof(int), stream);
    hist_kernel<<<(E + 255) / 256, 256, 0, stream>>>(dst, deg, E);
    scan1_kernel<<<nbScan, 256, 0, stream>>>(deg, incl, bsum, N);
    scan2_kernel<<<1, 256, 0, stream>>>(bsum, nbScan);
    scan3_kernel<<<nbScan, 256, 0, stream>>>(incl, bsum, row_ptr, N);
    scatter_kernel<<<(E + 255) / 256, 256, 0, stream>>>(src, dst, row_ptr, cursor, csr_src, E);

    for (int l = 0; l < L; ++l) {
        const float* x  = (l == 0) ? in_feats : out + (size_t)(l - 1) * N * DM;
        float*       xo = out + (size_t)l * N * DM;

        // z = x @ W[l]
        gemm_f32<<<dim3(DM / 64, gM), 256, 0, stream>>>(
            x, W + (size_t)l * DM * DM, z, N, DM, DM, nullptr, nullptr, nullptr);

        el_er_kernel<<<(N * NH + 255) / 256, 256, 0, stream>>>(
            z, attn_l + (size_t)l * NH * HD, attn_r + (size_t)l * NH * HD, el, er, N);

        // fused edge-softmax + aggregate + conv bias + PReLU -> hbuf... use z? we
        // need z during the kernel; write into hbuf then LN reads hbuf.
        gat_agg_kernel<<<(N + 3) / 4, 256, 0, stream>>>(
            row_ptr, csr_src, z, el, er, convb + (size_t)l * DM, a_conv + l, hbuf, N);

        // h = LN(hconv) -> z (reuse); hn = LN(h) -> hn
        layernorm2_kernel<<<(N + 3) / 4, 256, 0, stream>>>(
            hbuf, z, hn, ln_scale + (size_t)l * DM, ln_bias + (size_t)l * DM, N);

        // ffh = prelu(hn @ W1 + b1, a_ff)
        gemm_f32<<<dim3(DFF / 64, gM), 256, 0, stream>>>(
            hn, W1 + (size_t)l * DM * DFF, ffh, N, DFF, DM,
            b1 + (size_t)l * DFF, a_ff + l, nullptr);

        // xo = ffh @ W2 + b2 + h   (h lives in z)
        gemm_f32<<<dim3(DM / 64, gM), 256, 0, stream>>>(
            ffh, W2 + (size_t)l * DFF * DM, xo, N, DM, DFF,
            b2 + (size_t)l * DM, nullptr, z);
    }
}

// Round 3
// 936.674 us; speedup vs baseline: 2.1710x; 1.4907x over previous
//
#include <hip/hip_runtime.h>

#define DM 128
#define NH 8
#define HD 16
#define DFF 512

typedef __attribute__((ext_vector_type(8))) short bf16x8;
typedef __attribute__((ext_vector_type(4))) float f32x4;
typedef __attribute__((address_space(1))) const void gvoid;
typedef __attribute__((address_space(3))) void lvoid;

__device__ __forceinline__ short f2bf(float f) {
    union { float f; unsigned u; } v; v.f = f;
    unsigned r = v.u + 0x7fffu + ((v.u >> 16) & 1u);   // RNE
    return (short)(r >> 16);
}

// ---------------------------------------------------------------------------
// bf16 MFMA GEMM: C[M,Nc] = A[M,K] @ B[K,Nc], B supplied TRANSPOSED (BT[Nc][K]).
// 128x128 tile, BK=64, 256 thr = 4 waves (2x2), wave does 64x64 = 4x4 mfma
// 16x16x32 tiles. LDS in fragment-order blocks: block b = ks*8+g holds lanes'
// 16B frags for rows g*16..g*16+16, k ks*32..+32 -> global_load_lds-compatible
// AND conflict-free ds_read_b128.
// ---------------------------------------------------------------------------
__global__ __launch_bounds__(256) void gemm_bf16(
    const short* __restrict__ A, const short* __restrict__ BT,
    int M, int Nc, int K,
    const float* __restrict__ bias,     // [Nc] or nullptr
    const float* __restrict__ prelu_a,  // scalar or nullptr
    const float* __restrict__ residual, // [M,Nc] or nullptr
    float* __restrict__ Cf,             // fp32 out or nullptr
    short* __restrict__ Cbf)            // bf16 out or nullptr
{
    __shared__ short sA[16 * 512];   // 16 KB
    __shared__ short sB[16 * 512];   // 16 KB

    const int tid = threadIdx.x;
    const int wave = tid >> 6;
    const int lane = tid & 63;
    const int wm = wave >> 1;        // wave row 0..1
    const int wn = wave & 1;         // wave col 0..1
    const int bm = blockIdx.y * 128;
    const int bn = blockIdx.x * 128;

    const int lrow = lane & 15;          // row-in-group for staging & frags
    const int lkof = (lane >> 4) << 3;   // k offset 0/8/16/24

    f32x4 acc[4][4];
#pragma unroll
    for (int i = 0; i < 4; ++i)
#pragma unroll
        for (int j = 0; j < 4; ++j) acc[i][j] = (f32x4)0.0f;

    for (int kk = 0; kk < K; kk += 64) {
        // ---- stage A blocks wave*4..+4 and B blocks wave*4..+4 ----
#pragma unroll
        for (int i = 0; i < 4; ++i) {
            int b = wave * 4 + i;
            int ks = b >> 3, g = b & 7;
            int row = bm + g * 16 + lrow;
            row = (row < M) ? row : (M - 1);
            const short* gp = A + (size_t)row * K + kk + ks * 32 + lkof;
            __builtin_amdgcn_global_load_lds((gvoid*)gp, (lvoid*)(sA + b * 512), 16, 0, 0);
        }
#pragma unroll
        for (int i = 0; i < 4; ++i) {
            int b = wave * 4 + i;
            int ks = b >> 3, g = b & 7;
            int col = bn + g * 16 + lrow;           // Nc multiple of 128: no clamp
            const short* gp = BT + (size_t)col * K + kk + ks * 32 + lkof;
            __builtin_amdgcn_global_load_lds((gvoid*)gp, (lvoid*)(sB + b * 512), 16, 0, 0);
        }
        __syncthreads();

#pragma unroll
        for (int ks = 0; ks < 2; ++ks) {
            bf16x8 af[4], bfr[4];
#pragma unroll
            for (int i = 0; i < 4; ++i)
                af[i] = *(const bf16x8*)(sA + (ks * 8 + wm * 4 + i) * 512 + lane * 8);
#pragma unroll
            for (int j = 0; j < 4; ++j)
                bfr[j] = *(const bf16x8*)(sB + (ks * 8 + wn * 4 + j) * 512 + lane * 8);
#pragma unroll
            for (int i = 0; i < 4; ++i)
#pragma unroll
                for (int j = 0; j < 4; ++j)
                    acc[i][j] = __builtin_amdgcn_mfma_f32_16x16x32_bf16(
                        af[i], bfr[j], acc[i][j], 0, 0, 0);
        }
        __syncthreads();
    }

    // ---- epilogue: C/D layout col=lane&15, row=(lane>>4)*4+reg ----
    const int row0 = bm + wm * 64;
    const int col0 = bn + wn * 64;
    const int lr = (lane >> 4) * 2 * 2;  // (lane>>4)*4
    const int lc = lane & 15;
    float aslope = prelu_a ? *prelu_a : 0.0f;
#pragma unroll
    for (int i = 0; i < 4; ++i) {
#pragma unroll
        for (int r = 0; r < 4; ++r) {
            int row = row0 + i * 16 + lr + r;
            if (row >= M) continue;
#pragma unroll
            for (int j = 0; j < 4; ++j) {
                int col = col0 + j * 16 + lc;
                float v = acc[i][j][r];
                if (bias) v += bias[col];
                if (prelu_a) v = (v >= 0.0f) ? v : aslope * v;
                if (residual) v += residual[(size_t)row * Nc + col];
                if (Cf)  Cf[(size_t)row * Nc + col] = v;
                if (Cbf) Cbf[(size_t)row * Nc + col] = f2bf(v);
            }
        }
    }
}

// transpose + fp32->bf16: out[c*R + r] = bf16(in[r*C + c])
__global__ void wt_conv_kernel(const float* __restrict__ in, short* __restrict__ out,
                               int R, int C)
{
    int idx = blockIdx.x * blockDim.x + threadIdx.x;
    if (idx >= R * C) return;
    int r = idx / C, c = idx - r * C;
    out[(size_t)c * R + r] = f2bf(in[idx]);
}

__global__ void f2bf_kernel(const float* __restrict__ in, short* __restrict__ out, int n)
{
    int idx = blockIdx.x * blockDim.x + threadIdx.x;
    if (idx < n) out[idx] = f2bf(in[idx]);
}

// el[n,h] = sum_d z[n,h,d]*attn_l[h,d] ; er likewise
__global__ void el_er_kernel(const float* __restrict__ z,
                             const float* __restrict__ al,
                             const float* __restrict__ ar,
                             float* __restrict__ el, float* __restrict__ er, int N)
{
    int idx = blockIdx.x * blockDim.x + threadIdx.x;
    if (idx >= N * NH) return;
    int n = idx >> 3, h = idx & 7;
    const float* zp = z + (size_t)n * DM + h * HD;
    const float* alp = al + h * HD;
    const float* arp = ar + h * HD;
    float sl = 0.0f, sr = 0.0f;
#pragma unroll
    for (int d = 0; d < HD; ++d) {
        float zv = zp[d];
        sl = fmaf(zv, alp[d], sl);
        sr = fmaf(zv, arp[d], sr);
    }
    el[idx] = sl;
    er[idx] = sr;
}

// ---------------- CSR build (once per launch, reused across layers) --------
__global__ void hist_kernel(const int* __restrict__ dst, int* __restrict__ deg, int E)
{
    int e = blockIdx.x * blockDim.x + threadIdx.x;
    if (e < E) atomicAdd(&deg[dst[e]], 1);
}

__global__ void scan1_kernel(const int* __restrict__ deg, int* __restrict__ incl,
                             int* __restrict__ bsum, int N)
{
    __shared__ int sm[256];
    int i = blockIdx.x * 256 + threadIdx.x;
    int v = (i < N) ? deg[i] : 0;
    sm[threadIdx.x] = v;
    __syncthreads();
    for (int off = 1; off < 256; off <<= 1) {
        int t = (threadIdx.x >= off) ? sm[threadIdx.x - off] : 0;
        __syncthreads();
        sm[threadIdx.x] += t;
        __syncthreads();
    }
    if (i < N) incl[i] = sm[threadIdx.x];
    if (threadIdx.x == 255) bsum[blockIdx.x] = sm[255];
}

__global__ void scan2_kernel(int* __restrict__ bsum, int nb)
{
    __shared__ int sm[256];
    int v = (threadIdx.x < nb) ? bsum[threadIdx.x] : 0;
    sm[threadIdx.x] = v;
    __syncthreads();
    for (int off = 1; off < 256; off <<= 1) {
        int t = (threadIdx.x >= off) ? sm[threadIdx.x - off] : 0;
        __syncthreads();
        sm[threadIdx.x] += t;
        __syncthreads();
    }
    if (threadIdx.x < nb) bsum[threadIdx.x] = sm[threadIdx.x];
}

__global__ void scan3_kernel(const int* __restrict__ incl, const int* __restrict__ bsum,
                             int* __restrict__ row_ptr, int N)
{
    int i = blockIdx.x * 256 + threadIdx.x;
    if (i < N) {
        int off = (blockIdx.x > 0) ? bsum[blockIdx.x - 1] : 0;
        row_ptr[i + 1] = incl[i] + off;
    }
    if (i == 0) row_ptr[0] = 0;
}

__global__ void scatter_kernel(const int* __restrict__ src, const int* __restrict__ dst,
                               const int* __restrict__ row_ptr, int* __restrict__ cursor,
                               int* __restrict__ csr_src, int E)
{
    int e = blockIdx.x * blockDim.x + threadIdx.x;
    if (e >= E) return;
    int t = dst[e];
    int pos = atomicAdd(&cursor[t], 1);
    csr_src[row_ptr[t] + pos] = src[e];
}

// ---------------------------------------------------------------------------
// Fused edge-softmax + aggregate + bias + PReLU: one wave per dst node.
// ---------------------------------------------------------------------------
__global__ __launch_bounds__(256) void gat_agg_kernel(
    const int* __restrict__ row_ptr, const int* __restrict__ csr_src,
    const float* __restrict__ z, const float* __restrict__ el,
    const float* __restrict__ er, const float* __restrict__ cb,
    const float* __restrict__ a_conv, float* __restrict__ outp, int N)
{
    int wave = threadIdx.x >> 6, lane = threadIdx.x & 63;
    int t = blockIdx.x * 4 + wave;
    if (t >= N) return;
    int h0 = lane >> 4, h1 = h0 + 4;
    float er0 = er[t * NH + h0], er1 = er[t * NH + h1];
    int e0 = row_ptr[t], e1 = row_ptr[t + 1];
    float acc0 = 0.0f, acc1 = 0.0f, den0 = 0.0f, den1 = 0.0f;
    for (int e = e0; e < e1; ++e) {
        int s = csr_src[e];
        float v0 = el[s * NH + h0] + er0;
        float v1 = el[s * NH + h1] + er1;
        v0 = (v0 >= 0.0f) ? v0 : 0.2f * v0;
        v1 = (v1 >= 0.0f) ? v1 : 0.2f * v1;
        float w0 = __expf(v0), w1 = __expf(v1);
        den0 += w0; den1 += w1;
        const float* zp = z + (size_t)s * DM;
        acc0 = fmaf(w0, zp[lane], acc0);
        acc1 = fmaf(w1, zp[lane + 64], acc1);
    }
    float a = *a_conv;
    float o0 = acc0 / fmaxf(den0, 1e-9f) + cb[lane];
    float o1 = acc1 / fmaxf(den1, 1e-9f) + cb[lane + 64];
    outp[(size_t)t * DM + lane]      = (o0 >= 0.0f) ? o0 : a * o0;
    outp[(size_t)t * DM + lane + 64] = (o1 >= 0.0f) ? o1 : a * o1;
}

// Fused double-LayerNorm: h = LN(x) (fp32), hn = LN(h) (bf16). Wave per row.
__global__ __launch_bounds__(256) void layernorm2_kernel(
    const float* __restrict__ in, float* __restrict__ h_out, short* __restrict__ hn_out,
    const float* __restrict__ scale, const float* __restrict__ bias, int M)
{
    int wave = threadIdx.x >> 6;
    int lane = threadIdx.x & 63;
    int row = blockIdx.x * 4 + wave;
    if (row >= M) return;
    const float* r = in + (size_t)row * DM;
    float sc0 = scale[lane], sc1 = scale[lane + 64];
    float bi0 = bias[lane], bi1 = bias[lane + 64];

    float v0 = r[lane], v1 = r[lane + 64];
    float s = v0 + v1, ss = v0 * v0 + v1 * v1;
#pragma unroll
    for (int off = 32; off > 0; off >>= 1) {
        s += __shfl_xor(s, off, 64);
        ss += __shfl_xor(ss, off, 64);
    }
    float mean = s * (1.0f / 128.0f);
    float var = ss * (1.0f / 128.0f) - mean * mean;
    float rstd = rsqrtf(var + 1e-5f);
    float h0 = (v0 - mean) * rstd * sc0 + bi0;
    float h1 = (v1 - mean) * rstd * sc1 + bi1;
    h_out[(size_t)row * DM + lane]      = h0;
    h_out[(size_t)row * DM + lane + 64] = h1;

    s = h0 + h1; ss = h0 * h0 + h1 * h1;
#pragma unroll
    for (int off = 32; off > 0; off >>= 1) {
        s += __shfl_xor(s, off, 64);
        ss += __shfl_xor(ss, off, 64);
    }
    mean = s * (1.0f / 128.0f);
    var = ss * (1.0f / 128.0f) - mean * mean;
    rstd = rsqrtf(var + 1e-5f);
    hn_out[(size_t)row * DM + lane]      = f2bf((h0 - mean) * rstd * sc0 + bi0);
    hn_out[(size_t)row * DM + lane + 64] = f2bf((h1 - mean) * rstd * sc1 + bi1);
}

extern "C" void kernel_launch(void* const* d_in, const int* in_sizes, int n_in,
                              void* d_out, int out_size, void* d_ws, size_t ws_size,
                              hipStream_t stream)
{
    const float* in_feats = (const float*)d_in[0];
    const int*   src      = (const int*)d_in[1];
    const int*   dst      = (const int*)d_in[2];
    const float* W        = (const float*)d_in[3];
    const float* attn_l   = (const float*)d_in[4];
    const float* attn_r   = (const float*)d_in[5];
    const float* convb    = (const float*)d_in[6];
    const float* a_conv   = (const float*)d_in[7];
    const float* ln_scale = (const float*)d_in[8];
    const float* ln_bias  = (const float*)d_in[9];
    const float* W1       = (const float*)d_in[10];
    const float* b1       = (const float*)d_in[11];
    const float* W2       = (const float*)d_in[12];
    const float* b2       = (const float*)d_in[13];
    const float* a_ff     = (const float*)d_in[14];
    float* out = (float*)d_out;

    const int N = in_sizes[0] / DM;
    const int E = in_sizes[1];
    const int L = in_sizes[7];

    char* wsb = (char*)d_ws;
    size_t off = 0;
    auto alloc = [&](size_t bytes) { char* p = wsb + off; off += (bytes + 255) & ~(size_t)255; return p; };

    float* z     = (float*)alloc((size_t)N * DM * sizeof(float));   // z, then h
    float* el    = (float*)alloc((size_t)N * NH * sizeof(float));
    float* er    = (float*)alloc((size_t)N * NH * sizeof(float));
    float* hbuf  = (float*)alloc((size_t)N * DM * sizeof(float));
    short* hn_bf = (short*)alloc((size_t)N * DM * sizeof(short));
    short* ffh_bf= (short*)alloc((size_t)N * DFF * sizeof(short));
    short* x_bf  = (short*)alloc((size_t)N * DM * sizeof(short));
    short* Wt    = (short*)alloc((size_t)L * DM * DM * sizeof(short));    // [l][n=DM][k=DM]
    short* W1t   = (short*)alloc((size_t)L * DFF * DM * sizeof(short));   // [l][n=DFF][k=DM]
    short* W2t   = (short*)alloc((size_t)L * DM * DFF * sizeof(short));   // [l][n=DM][k=DFF]
    int* deg     = (int*)alloc((size_t)N * sizeof(int));
    int* incl    = (int*)alloc((size_t)N * sizeof(int));
    int* bsum    = (int*)alloc(256 * sizeof(int));
    int* row_ptr = (int*)alloc((size_t)(N + 1) * sizeof(int));
    int* cursor  = (int*)alloc((size_t)N * sizeof(int));
    int* csr_src = (int*)alloc((size_t)E * sizeof(int));

    const int gM128 = (N + 127) / 128;
    const int nbScan = (N + 255) / 256;

    // ---- CSR by dst ----
    hipMemsetAsync(deg, 0, (size_t)N * sizeof(int), stream);
    hipMemsetAsync(cursor, 0, (size_t)N * sizeof(int), stream);
    hist_kernel<<<(E + 255) / 256, 256, 0, stream>>>(dst, deg, E);
    scan1_kernel<<<nbScan, 256, 0, stream>>>(deg, incl, bsum, N);
    scan2_kernel<<<1, 256, 0, stream>>>(bsum, nbScan);
    scan3_kernel<<<nbScan, 256, 0, stream>>>(incl, bsum, row_ptr, N);
    scatter_kernel<<<(E + 255) / 256, 256, 0, stream>>>(src, dst, row_ptr, cursor, csr_src, E);

    // ---- weight convert+transpose, input convert ----
    for (int l = 0; l < L; ++l) {
        wt_conv_kernel<<<(DM * DM + 255) / 256, 256, 0, stream>>>(
            W + (size_t)l * DM * DM, Wt + (size_t)l * DM * DM, DM, DM);
        wt_conv_kernel<<<(DM * DFF + 255) / 256, 256, 0, stream>>>(
            W1 + (size_t)l * DM * DFF, W1t + (size_t)l * DFF * DM, DM, DFF);
        wt_conv_kernel<<<(DFF * DM + 255) / 256, 256, 0, stream>>>(
            W2 + (size_t)l * DFF * DM, W2t + (size_t)l * DM * DFF, DFF, DM);
    }
    f2bf_kernel<<<(N * DM + 255) / 256, 256, 0, stream>>>(in_feats, x_bf, N * DM);

    for (int l = 0; l < L; ++l) {
        float* xo = out + (size_t)l * N * DM;

        // z = x_bf @ W[l]   (fp32 out)
        gemm_bf16<<<dim3(1, gM128), 256, 0, stream>>>(
            x_bf, Wt + (size_t)l * DM * DM, N, DM, DM,
            nullptr, nullptr, nullptr, z, nullptr);

        el_er_kernel<<<(N * NH + 255) / 256, 256, 0, stream>>>(
            z, attn_l + (size_t)l * NH * HD, attn_r + (size_t)l * NH * HD, el, er, N);

        gat_agg_kernel<<<(N + 3) / 4, 256, 0, stream>>>(
            row_ptr, csr_src, z, el, er, convb + (size_t)l * DM, a_conv + l, hbuf, N);

        // h = LN(hconv) -> z (fp32, residual); hn -> bf16
        layernorm2_kernel<<<(N + 3) / 4, 256, 0, stream>>>(
            hbuf, z, hn_bf, ln_scale + (size_t)l * DM, ln_bias + (size_t)l * DM, N);

        // ffh_bf = bf16(prelu(hn @ W1 + b1, a_ff))
        gemm_bf16<<<dim3(DFF / 128, gM128), 256, 0, stream>>>(
            hn_bf, W1t + (size_t)l * DFF * DM, N, DFF, DM,
            b1 + (size_t)l * DFF, a_ff + l, nullptr, nullptr, ffh_bf);

        // xo = ffh @ W2 + b2 + h ; also x_bf = bf16(xo) for next layer
        gemm_bf16<<<dim3(1, gM128), 256, 0, stream>>>(
            ffh_bf, W2t + (size_t)l * DM * DFF, N, DM, DFF,
            b2 + (size_t)l * DM, nullptr, z, xo, x_bf);
    }
}

// Round 4
// 866.122 us; speedup vs baseline: 2.3478x; 1.0815x over previous
//
#include <hip/hip_runtime.h>

#define DM 128
#define NH 8
#define HD 16
#define DFF 512

typedef __attribute__((ext_vector_type(8))) short bf16x8;
typedef __attribute__((ext_vector_type(4))) float f32x4;
typedef __attribute__((address_space(1))) const void gvoid;
typedef __attribute__((address_space(3))) void lvoid;

__device__ __forceinline__ short f2bf(float f) {
    union { float f; unsigned u; } v; v.f = f;
    unsigned r = v.u + 0x7fffu + ((v.u >> 16) & 1u);   // RNE
    return (short)(r >> 16);
}
__device__ __forceinline__ float bf2f(unsigned short b) {
    union { unsigned u; float f; } v; v.u = ((unsigned)b) << 16; return v.f;
}

// ---------------------------------------------------------------------------
// Whole-K bf16 MFMA GEMM for K=128: C[M,Nc] = A[M,128] @ BT[Nc,128]^T.
// 128x128 tile. A-tile 32KB + B-stripe 32KB staged in ONE shot, ONE barrier,
// B-frags register-resident, 64 MFMA/wave. LDS fragment-order blocks
// (b = ks*8 + g, 512 shorts each) -> global_load_lds width16 + conflict-free
// ds_read_b128.
// ---------------------------------------------------------------------------
__global__ __launch_bounds__(256) void gemm_k128(
    const short* __restrict__ A, const short* __restrict__ BT,
    int M, int Nc,
    const float* __restrict__ bias, const float* __restrict__ prelu_a,
    const float* __restrict__ residual,
    float* __restrict__ Cf, short* __restrict__ Cbf)
{
    const int K = 128;
    __shared__ short sA[32 * 512];   // 32 KB
    __shared__ short sB[32 * 512];   // 32 KB

    const int tid = threadIdx.x;
    const int wave = tid >> 6;
    const int lane = tid & 63;
    const int wm = wave >> 1, wn = wave & 1;
    const int bm = blockIdx.y * 128;
    const int bn = blockIdx.x * 128;
    const int lrow = lane & 15;
    const int lkof = (lane >> 4) << 3;

    // stage A blocks [wave*8, wave*8+8) and same for B
#pragma unroll
    for (int i = 0; i < 8; ++i) {
        int b = wave * 8 + i;
        int ks = b >> 3, g = b & 7;
        int row = bm + g * 16 + lrow;
        row = (row < M) ? row : (M - 1);
        const short* gp = A + (size_t)row * K + ks * 32 + lkof;
        __builtin_amdgcn_global_load_lds((gvoid*)gp, (lvoid*)(sA + b * 512), 16, 0, 0);
    }
#pragma unroll
    for (int i = 0; i < 8; ++i) {
        int b = wave * 8 + i;
        int ks = b >> 3, g = b & 7;
        int col = bn + g * 16 + lrow;
        const short* gp = BT + (size_t)col * K + ks * 32 + lkof;
        __builtin_amdgcn_global_load_lds((gvoid*)gp, (lvoid*)(sB + b * 512), 16, 0, 0);
    }

    f32x4 acc[4][4];
#pragma unroll
    for (int i = 0; i < 4; ++i)
#pragma unroll
        for (int j = 0; j < 4; ++j) acc[i][j] = (f32x4)0.0f;

    __syncthreads();

    // B-frags to registers (wave's 64-col stripe, all K)
    bf16x8 bfr[4][4];
#pragma unroll
    for (int ks = 0; ks < 4; ++ks)
#pragma unroll
        for (int j = 0; j < 4; ++j)
            bfr[ks][j] = *(const bf16x8*)(sB + (ks * 8 + wn * 4 + j) * 512 + lane * 8);

#pragma unroll
    for (int ks = 0; ks < 4; ++ks) {
        bf16x8 af[4];
#pragma unroll
        for (int i = 0; i < 4; ++i)
            af[i] = *(const bf16x8*)(sA + (ks * 8 + wm * 4 + i) * 512 + lane * 8);
#pragma unroll
        for (int i = 0; i < 4; ++i)
#pragma unroll
            for (int j = 0; j < 4; ++j)
                acc[i][j] = __builtin_amdgcn_mfma_f32_16x16x32_bf16(
                    af[i], bfr[ks][j], acc[i][j], 0, 0, 0);
    }

    const int row0 = bm + wm * 64;
    const int col0 = bn + wn * 64;
    const int lr = (lane >> 4) * 4;
    const int lc = lane & 15;
    float aslope = prelu_a ? *prelu_a : 0.0f;
#pragma unroll
    for (int i = 0; i < 4; ++i) {
#pragma unroll
        for (int r = 0; r < 4; ++r) {
            int row = row0 + i * 16 + lr + r;
            if (row >= M) continue;
#pragma unroll
            for (int j = 0; j < 4; ++j) {
                int col = col0 + j * 16 + lc;
                float v = acc[i][j][r];
                if (bias) v += bias[col];
                if (prelu_a) v = (v >= 0.0f) ? v : aslope * v;
                if (residual) v += residual[(size_t)row * Nc + col];
                if (Cf)  Cf[(size_t)row * Nc + col] = v;
                if (Cbf) Cbf[(size_t)row * Nc + col] = f2bf(v);
            }
        }
    }
}

// ---------------------------------------------------------------------------
// Double-buffered bf16 GEMM, BK=64 (for K=512): prefetch tile k+1 after the
// barrier while computing tile k. One barrier per K-iter.
// ---------------------------------------------------------------------------
__global__ __launch_bounds__(256) void gemm_dbuf(
    const short* __restrict__ A, const short* __restrict__ BT,
    int M, int Nc, int K,
    const float* __restrict__ bias, const float* __restrict__ prelu_a,
    const float* __restrict__ residual,
    float* __restrict__ Cf, short* __restrict__ Cbf)
{
    __shared__ short sA[2][16 * 512];
    __shared__ short sB[2][16 * 512];

    const int tid = threadIdx.x;
    const int wave = tid >> 6;
    const int lane = tid & 63;
    const int wm = wave >> 1, wn = wave & 1;
    const int bm = blockIdx.y * 128;
    const int bn = blockIdx.x * 128;
    const int lrow = lane & 15;
    const int lkof = (lane >> 4) << 3;

    auto stage = [&](int buf, int kk) {
#pragma unroll
        for (int i = 0; i < 4; ++i) {
            int b = wave * 4 + i;
            int ks = b >> 3, g = b & 7;
            int row = bm + g * 16 + lrow;
            row = (row < M) ? row : (M - 1);
            const short* gp = A + (size_t)row * K + kk + ks * 32 + lkof;
            __builtin_amdgcn_global_load_lds((gvoid*)gp, (lvoid*)(sA[buf] + b * 512), 16, 0, 0);
        }
#pragma unroll
        for (int i = 0; i < 4; ++i) {
            int b = wave * 4 + i;
            int ks = b >> 3, g = b & 7;
            int col = bn + g * 16 + lrow;
            const short* gp = BT + (size_t)col * K + kk + ks * 32 + lkof;
            __builtin_amdgcn_global_load_lds((gvoid*)gp, (lvoid*)(sB[buf] + b * 512), 16, 0, 0);
        }
    };

    f32x4 acc[4][4];
#pragma unroll
    for (int i = 0; i < 4; ++i)
#pragma unroll
        for (int j = 0; j < 4; ++j) acc[i][j] = (f32x4)0.0f;

    stage(0, 0);
    int cur = 0;
    for (int kk = 0; kk < K; kk += 64) {
        __syncthreads();
        if (kk + 64 < K) stage(cur ^ 1, kk + 64);
#pragma unroll
        for (int ks = 0; ks < 2; ++ks) {
            bf16x8 af[4], bfr[4];
#pragma unroll
            for (int i = 0; i < 4; ++i)
                af[i] = *(const bf16x8*)(sA[cur] + (ks * 8 + wm * 4 + i) * 512 + lane * 8);
#pragma unroll
            for (int j = 0; j < 4; ++j)
                bfr[j] = *(const bf16x8*)(sB[cur] + (ks * 8 + wn * 4 + j) * 512 + lane * 8);
#pragma unroll
            for (int i = 0; i < 4; ++i)
#pragma unroll
                for (int j = 0; j < 4; ++j)
                    acc[i][j] = __builtin_amdgcn_mfma_f32_16x16x32_bf16(
                        af[i], bfr[j], acc[i][j], 0, 0, 0);
        }
        cur ^= 1;
    }

    const int row0 = bm + wm * 64;
    const int col0 = bn + wn * 64;
    const int lr = (lane >> 4) * 4;
    const int lc = lane & 15;
    float aslope = prelu_a ? *prelu_a : 0.0f;
#pragma unroll
    for (int i = 0; i < 4; ++i) {
#pragma unroll
        for (int r = 0; r < 4; ++r) {
            int row = row0 + i * 16 + lr + r;
            if (row >= M) continue;
#pragma unroll
            for (int j = 0; j < 4; ++j) {
                int col = col0 + j * 16 + lc;
                float v = acc[i][j][r];
                if (bias) v += bias[col];
                if (prelu_a) v = (v >= 0.0f) ? v : aslope * v;
                if (residual) v += residual[(size_t)row * Nc + col];
                if (Cf)  Cf[(size_t)row * Nc + col] = v;
                if (Cbf) Cbf[(size_t)row * Nc + col] = f2bf(v);
            }
        }
    }
}

// transpose + fp32->bf16: out[c*R + r] = bf16(in[r*C + c])
__global__ void wt_conv_kernel(const float* __restrict__ in, short* __restrict__ out,
                               int R, int C)
{
    int idx = blockIdx.x * blockDim.x + threadIdx.x;
    if (idx >= R * C) return;
    int r = idx / C, c = idx - r * C;
    out[(size_t)c * R + r] = f2bf(in[idx]);
}

__global__ void f2bf_kernel(const float* __restrict__ in, short* __restrict__ out, int n)
{
    int idx = blockIdx.x * blockDim.x + threadIdx.x;
    if (idx < n) out[idx] = f2bf(in[idx]);
}

// el/er from bf16 z
__global__ void el_er_kernel(const short* __restrict__ z,
                             const float* __restrict__ al,
                             const float* __restrict__ ar,
                             float* __restrict__ el, float* __restrict__ er, int N)
{
    int idx = blockIdx.x * blockDim.x + threadIdx.x;
    if (idx >= N * NH) return;
    int n = idx >> 3, h = idx & 7;
    const unsigned* zp = (const unsigned*)(z + (size_t)n * DM + h * HD);
    const float* alp = al + h * HD;
    const float* arp = ar + h * HD;
    float sl = 0.0f, sr = 0.0f;
#pragma unroll
    for (int d2 = 0; d2 < 8; ++d2) {
        unsigned u = zp[d2];
        float z0 = bf2f((unsigned short)(u & 0xffff));
        float z1 = bf2f((unsigned short)(u >> 16));
        sl = fmaf(z0, alp[2 * d2], sl);     sl = fmaf(z1, alp[2 * d2 + 1], sl);
        sr = fmaf(z0, arp[2 * d2], sr);     sr = fmaf(z1, arp[2 * d2 + 1], sr);
    }
    el[idx] = sl;
    er[idx] = sr;
}

// ---------------- CSR build ----------------
__global__ void hist_kernel(const int* __restrict__ dst, int* __restrict__ deg, int E)
{
    int e = blockIdx.x * blockDim.x + threadIdx.x;
    if (e < E) atomicAdd(&deg[dst[e]], 1);
}

__global__ void scan1_kernel(const int* __restrict__ deg, int* __restrict__ incl,
                             int* __restrict__ bsum, int N)
{
    __shared__ int sm[256];
    int i = blockIdx.x * 256 + threadIdx.x;
    int v = (i < N) ? deg[i] : 0;
    sm[threadIdx.x] = v;
    __syncthreads();
    for (int off = 1; off < 256; off <<= 1) {
        int t = (threadIdx.x >= off) ? sm[threadIdx.x - off] : 0;
        __syncthreads();
        sm[threadIdx.x] += t;
        __syncthreads();
    }
    if (i < N) incl[i] = sm[threadIdx.x];
    if (threadIdx.x == 255) bsum[blockIdx.x] = sm[255];
}

__global__ void scan2_kernel(int* __restrict__ bsum, int nb)
{
    __shared__ int sm[256];
    int v = (threadIdx.x < nb) ? bsum[threadIdx.x] : 0;
    sm[threadIdx.x] = v;
    __syncthreads();
    for (int off = 1; off < 256; off <<= 1) {
        int t = (threadIdx.x >= off) ? sm[threadIdx.x - off] : 0;
        __syncthreads();
        sm[threadIdx.x] += t;
        __syncthreads();
    }
    if (threadIdx.x < nb) bsum[threadIdx.x] = sm[threadIdx.x];
}

__global__ void scan3_kernel(const int* __restrict__ incl, const int* __restrict__ bsum,
                             int* __restrict__ row_ptr, int N)
{
    int i = blockIdx.x * 256 + threadIdx.x;
    if (i < N) {
        int off = (blockIdx.x > 0) ? bsum[blockIdx.x - 1] : 0;
        row_ptr[i + 1] = incl[i] + off;
    }
    if (i == 0) row_ptr[0] = 0;
}

__global__ void scatter_kernel(const int* __restrict__ src, const int* __restrict__ dst,
                               const int* __restrict__ row_ptr, int* __restrict__ cursor,
                               int* __restrict__ csr_src, int E)
{
    int e = blockIdx.x * blockDim.x + threadIdx.x;
    if (e >= E) return;
    int t = dst[e];
    int pos = atomicAdd(&cursor[t], 1);
    csr_src[row_ptr[t] + pos] = src[e];
}

// ---------------------------------------------------------------------------
// Fused: edge-softmax + aggregate (bf16 z) + conv bias + PReLU + LN1 + LN2.
// One wave per dst node. Lane owns channels 2*lane, 2*lane+1 (same head
// h = lane>>3). Writes h (fp32, residual) and hn (bf16, FF input).
// ---------------------------------------------------------------------------
__global__ __launch_bounds__(256) void gat_agg_ln_kernel(
    const int* __restrict__ row_ptr, const int* __restrict__ csr_src,
    const short* __restrict__ z, const float* __restrict__ el,
    const float* __restrict__ er, const float* __restrict__ cb,
    const float* __restrict__ a_conv,
    const float* __restrict__ scale, const float* __restrict__ bias,
    float* __restrict__ h_out, short* __restrict__ hn_out, int N)
{
    int wave = threadIdx.x >> 6, lane = threadIdx.x & 63;
    int t = blockIdx.x * 4 + wave;
    if (t >= N) return;
    int h = lane >> 3;
    int c0 = 2 * lane, c1 = c0 + 1;
    float er_t = er[t * NH + h];
    int e0 = row_ptr[t], e1 = row_ptr[t + 1];
    float acc0 = 0.0f, acc1 = 0.0f, den = 0.0f;
    const unsigned* zw = (const unsigned*)z;
    for (int e = e0; e < e1; ++e) {
        int s = csr_src[e];
        float v = el[s * NH + h] + er_t;
        v = (v >= 0.0f) ? v : 0.2f * v;
        float w = __expf(v);
        den += w;
        unsigned u = zw[(size_t)s * 64 + lane];
        acc0 = fmaf(w, bf2f((unsigned short)(u & 0xffff)), acc0);
        acc1 = fmaf(w, bf2f((unsigned short)(u >> 16)), acc1);
    }
    float a = *a_conv;
    float inv = 1.0f / fmaxf(den, 1e-9f);
    float o0 = acc0 * inv + cb[c0];
    float o1 = acc1 * inv + cb[c1];
    o0 = (o0 >= 0.0f) ? o0 : a * o0;
    o1 = (o1 >= 0.0f) ? o1 : a * o1;

    float sc0 = scale[c0], sc1 = scale[c1];
    float bi0 = bias[c0], bi1 = bias[c1];

    // LN1
    float s1 = o0 + o1, ss = o0 * o0 + o1 * o1;
#pragma unroll
    for (int off = 32; off > 0; off >>= 1) {
        s1 += __shfl_xor(s1, off, 64);
        ss += __shfl_xor(ss, off, 64);
    }
    float mean = s1 * (1.0f / 128.0f);
    float var = ss * (1.0f / 128.0f) - mean * mean;
    float rstd = rsqrtf(var + 1e-5f);
    float h0 = (o0 - mean) * rstd * sc0 + bi0;
    float h1 = (o1 - mean) * rstd * sc1 + bi1;
    ((float2*)h_out)[(size_t)t * 64 + lane] = make_float2(h0, h1);

    // LN2
    s1 = h0 + h1; ss = h0 * h0 + h1 * h1;
#pragma unroll
    for (int off = 32; off > 0; off >>= 1) {
        s1 += __shfl_xor(s1, off, 64);
        ss += __shfl_xor(ss, off, 64);
    }
    mean = s1 * (1.0f / 128.0f);
    var = ss * (1.0f / 128.0f) - mean * mean;
    rstd = rsqrtf(var + 1e-5f);
    unsigned lo = (unsigned short)f2bf((h0 - mean) * rstd * sc0 + bi0);
    unsigned hi = (unsigned short)f2bf((h1 - mean) * rstd * sc1 + bi1);
    ((unsigned*)hn_out)[(size_t)t * 64 + lane] = lo | (hi << 16);
}

extern "C" void kernel_launch(void* const* d_in, const int* in_sizes, int n_in,
                              void* d_out, int out_size, void* d_ws, size_t ws_size,
                              hipStream_t stream)
{
    const float* in_feats = (const float*)d_in[0];
    const int*   src      = (const int*)d_in[1];
    const int*   dst      = (const int*)d_in[2];
    const float* W        = (const float*)d_in[3];
    const float* attn_l   = (const float*)d_in[4];
    const float* attn_r   = (const float*)d_in[5];
    const float* convb    = (const float*)d_in[6];
    const float* a_conv   = (const float*)d_in[7];
    const float* ln_scale = (const float*)d_in[8];
    const float* ln_bias  = (const float*)d_in[9];
    const float* W1       = (const float*)d_in[10];
    const float* b1       = (const float*)d_in[11];
    const float* W2       = (const float*)d_in[12];
    const float* b2       = (const float*)d_in[13];
    const float* a_ff     = (const float*)d_in[14];
    float* out = (float*)d_out;

    const int N = in_sizes[0] / DM;
    const int E = in_sizes[1];
    const int L = in_sizes[7];

    char* wsb = (char*)d_ws;
    size_t off = 0;
    auto alloc = [&](size_t bytes) { char* p = wsb + off; off += (bytes + 255) & ~(size_t)255; return p; };

    short* z_bf  = (short*)alloc((size_t)N * DM * sizeof(short));
    float* el    = (float*)alloc((size_t)N * NH * sizeof(float));
    float* er    = (float*)alloc((size_t)N * NH * sizeof(float));
    float* hbuf  = (float*)alloc((size_t)N * DM * sizeof(float));   // h (LN1 out, residual)
    short* hn_bf = (short*)alloc((size_t)N * DM * sizeof(short));
    short* ffh_bf= (short*)alloc((size_t)N * DFF * sizeof(short));
    short* x_bf  = (short*)alloc((size_t)N * DM * sizeof(short));
    short* Wt    = (short*)alloc((size_t)L * DM * DM * sizeof(short));
    short* W1t   = (short*)alloc((size_t)L * DFF * DM * sizeof(short));
    short* W2t   = (short*)alloc((size_t)L * DM * DFF * sizeof(short));
    int* deg     = (int*)alloc((size_t)N * sizeof(int));
    int* incl    = (int*)alloc((size_t)N * sizeof(int));
    int* bsum    = (int*)alloc(256 * sizeof(int));
    int* row_ptr = (int*)alloc((size_t)(N + 1) * sizeof(int));
    int* cursor  = (int*)alloc((size_t)N * sizeof(int));
    int* csr_src = (int*)alloc((size_t)E * sizeof(int));

    const int gM128 = (N + 127) / 128;
    const int nbScan = (N + 255) / 256;

    // ---- CSR by dst ----
    hipMemsetAsync(deg, 0, (size_t)N * sizeof(int), stream);
    hipMemsetAsync(cursor, 0, (size_t)N * sizeof(int), stream);
    hist_kernel<<<(E + 255) / 256, 256, 0, stream>>>(dst, deg, E);
    scan1_kernel<<<nbScan, 256, 0, stream>>>(deg, incl, bsum, N);
    scan2_kernel<<<1, 256, 0, stream>>>(bsum, nbScan);
    scan3_kernel<<<nbScan, 256, 0, stream>>>(incl, bsum, row_ptr, N);
    scatter_kernel<<<(E + 255) / 256, 256, 0, stream>>>(src, dst, row_ptr, cursor, csr_src, E);

    // ---- weight convert+transpose, input convert ----
    for (int l = 0; l < L; ++l) {
        wt_conv_kernel<<<(DM * DM + 255) / 256, 256, 0, stream>>>(
            W + (size_t)l * DM * DM, Wt + (size_t)l * DM * DM, DM, DM);
        wt_conv_kernel<<<(DM * DFF + 255) / 256, 256, 0, stream>>>(
            W1 + (size_t)l * DM * DFF, W1t + (size_t)l * DFF * DM, DM, DFF);
        wt_conv_kernel<<<(DFF * DM + 255) / 256, 256, 0, stream>>>(
            W2 + (size_t)l * DFF * DM, W2t + (size_t)l * DM * DFF, DFF, DM);
    }
    f2bf_kernel<<<(N * DM + 255) / 256, 256, 0, stream>>>(in_feats, x_bf, N * DM);

    for (int l = 0; l < L; ++l) {
        float* xo = out + (size_t)l * N * DM;

        // z_bf = bf16(x_bf @ W[l])
        gemm_k128<<<dim3(1, gM128), 256, 0, stream>>>(
            x_bf, Wt + (size_t)l * DM * DM, N, DM,
            nullptr, nullptr, nullptr, nullptr, z_bf);

        el_er_kernel<<<(N * NH + 255) / 256, 256, 0, stream>>>(
            z_bf, attn_l + (size_t)l * NH * HD, attn_r + (size_t)l * NH * HD, el, er, N);

        // aggregate + bias + prelu + LN1 (-> hbuf fp32) + LN2 (-> hn_bf)
        gat_agg_ln_kernel<<<(N + 3) / 4, 256, 0, stream>>>(
            row_ptr, csr_src, z_bf, el, er, convb + (size_t)l * DM, a_conv + l,
            ln_scale + (size_t)l * DM, ln_bias + (size_t)l * DM, hbuf, hn_bf, N);

        // ffh_bf = bf16(prelu(hn @ W1 + b1, a_ff))
        gemm_k128<<<dim3(DFF / 128, gM128), 256, 0, stream>>>(
            hn_bf, W1t + (size_t)l * DFF * DM, N, DFF,
            b1 + (size_t)l * DFF, a_ff + l, nullptr, nullptr, ffh_bf);

        // xo = ffh @ W2 + b2 + h ; x_bf = bf16(xo)
        gemm_dbuf<<<dim3(1, gM128), 256, 0, stream>>>(
            ffh_bf, W2t + (size_t)l * DM * DFF, N, DM, DFF,
            b2 + (size_t)l * DM, nullptr, hbuf, xo, x_bf);
    }
}

// Round 5
// 818.495 us; speedup vs baseline: 2.4845x; 1.0582x over previous
//
#include <hip/hip_runtime.h>

#define DM 128
#define NH 8
#define HD 16
#define DFF 512

typedef __attribute__((ext_vector_type(8))) short bf16x8;
typedef __attribute__((ext_vector_type(4))) float f32x4;

__device__ __forceinline__ short f2bf(float f) {
    union { float f; unsigned u; } v; v.f = f;
    unsigned r = v.u + 0x7fffu + ((v.u >> 16) & 1u);   // RNE
    return (short)(r >> 16);
}
__device__ __forceinline__ float bf2f(unsigned short b) {
    union { unsigned u; float f; } v; v.u = ((unsigned)b) << 16; return v.f;
}

// ---------------------------------------------------------------------------
// LDS-free bf16 MFMA GEMM. C[M,Nc] = A[M,K] @ BT[Nc,K]^T.
// MFMA fragments are 16 contiguous bytes in K-major layout, so each lane
// loads its A/B fragment straight from global (coalesced dwordx4: lanes
// l,l+16,l+32,l+48 cover 64 contiguous bytes of one row). No LDS, no
// barriers; register double-buffer prefetches ks+1 frags during ks MFMAs.
// 128x128 tile, 4 waves 2x2, 4x4 16x16x32 MFMA tiles per wave.
// ---------------------------------------------------------------------------
template<int K>
__global__ __launch_bounds__(256) void gemm_direct(
    const short* __restrict__ A, const short* __restrict__ BT,
    int M, int Nc,
    const float* __restrict__ bias, const float* __restrict__ prelu_a,
    const float* __restrict__ residual,
    float* __restrict__ Cf, short* __restrict__ Cbf)
{
    constexpr int nK = K / 32;
    const int tid = threadIdx.x;
    const int wave = tid >> 6, lane = tid & 63;
    const int wm = wave >> 1, wn = wave & 1;
    const int bm = blockIdx.y * 128, bn = blockIdx.x * 128;
    const int fr = lane & 15;           // fragment row/col within 16
    const int fk = (lane >> 4) << 3;    // k element offset 0/8/16/24

    const short* Ab[4];
    const short* Bb[4];
#pragma unroll
    for (int i = 0; i < 4; ++i) {
        int row = bm + wm * 64 + i * 16 + fr;
        row = (row < M) ? row : (M - 1);
        Ab[i] = A + (size_t)row * K + fk;
    }
#pragma unroll
    for (int j = 0; j < 4; ++j) {
        int col = bn + wn * 64 + j * 16 + fr;   // Nc multiple of 128
        Bb[j] = BT + (size_t)col * K + fk;
    }

    f32x4 acc[4][4];
#pragma unroll
    for (int i = 0; i < 4; ++i)
#pragma unroll
        for (int j = 0; j < 4; ++j) acc[i][j] = (f32x4)0.0f;

    bf16x8 af[2][4], bfr[2][4];
#pragma unroll
    for (int i = 0; i < 4; ++i) {
        af[0][i]  = *(const bf16x8*)(Ab[i]);
        bfr[0][i] = *(const bf16x8*)(Bb[i]);
    }

#pragma unroll
    for (int ks = 0; ks < nK; ++ks) {
        const int cur = ks & 1;
        if (ks + 1 < nK) {
#pragma unroll
            for (int i = 0; i < 4; ++i) {
                af[cur ^ 1][i]  = *(const bf16x8*)(Ab[i] + (ks + 1) * 32);
                bfr[cur ^ 1][i] = *(const bf16x8*)(Bb[i] + (ks + 1) * 32);
            }
        }
#pragma unroll
        for (int i = 0; i < 4; ++i)
#pragma unroll
            for (int j = 0; j < 4; ++j)
                acc[i][j] = __builtin_amdgcn_mfma_f32_16x16x32_bf16(
                    af[cur][i], bfr[cur][j], acc[i][j], 0, 0, 0);
    }

    const int row0 = bm + wm * 64;
    const int col0 = bn + wn * 64;
    const int lr = (lane >> 4) * 4;
    const int lc = lane & 15;
    float aslope = prelu_a ? *prelu_a : 0.0f;
#pragma unroll
    for (int i = 0; i < 4; ++i) {
#pragma unroll
        for (int r = 0; r < 4; ++r) {
            int row = row0 + i * 16 + lr + r;
            if (row >= M) continue;
#pragma unroll
            for (int j = 0; j < 4; ++j) {
                int col = col0 + j * 16 + lc;
                float v = acc[i][j][r];
                if (bias) v += bias[col];
                if (prelu_a) v = (v >= 0.0f) ? v : aslope * v;
                if (residual) v += residual[(size_t)row * Nc + col];
                if (Cf)  Cf[(size_t)row * Nc + col] = v;
                if (Cbf) Cbf[(size_t)row * Nc + col] = f2bf(v);
            }
        }
    }
}

// transpose + fp32->bf16 for all L layers: out[l][c][r] = bf16(in[l][r][c])
__global__ void wt_conv_kernel(const float* __restrict__ in, short* __restrict__ out,
                               int R, int C, int nL)
{
    int idx = blockIdx.x * blockDim.x + threadIdx.x;
    if (idx >= nL * R * C) return;
    int l = idx / (R * C);
    int rem = idx - l * (R * C);
    int r = rem / C, c = rem - r * C;
    out[(size_t)l * R * C + (size_t)c * R + r] = f2bf(in[idx]);
}

__global__ void f2bf_kernel(const float* __restrict__ in, short* __restrict__ out, int n)
{
    int idx = blockIdx.x * blockDim.x + threadIdx.x;
    if (idx < n) out[idx] = f2bf(in[idx]);
}

// el/er from bf16 z
__global__ void el_er_kernel(const short* __restrict__ z,
                             const float* __restrict__ al,
                             const float* __restrict__ ar,
                             float* __restrict__ el, float* __restrict__ er, int N)
{
    int idx = blockIdx.x * blockDim.x + threadIdx.x;
    if (idx >= N * NH) return;
    int n = idx >> 3, h = idx & 7;
    const unsigned* zp = (const unsigned*)(z + (size_t)n * DM + h * HD);
    const float* alp = al + h * HD;
    const float* arp = ar + h * HD;
    float sl = 0.0f, sr = 0.0f;
#pragma unroll
    for (int d2 = 0; d2 < 8; ++d2) {
        unsigned u = zp[d2];
        float z0 = bf2f((unsigned short)(u & 0xffff));
        float z1 = bf2f((unsigned short)(u >> 16));
        sl = fmaf(z0, alp[2 * d2], sl);     sl = fmaf(z1, alp[2 * d2 + 1], sl);
        sr = fmaf(z0, arp[2 * d2], sr);     sr = fmaf(z1, arp[2 * d2 + 1], sr);
    }
    el[idx] = sl;
    er[idx] = sr;
}

// ---------------- CSR build ----------------
__global__ void hist_kernel(const int* __restrict__ dst, int* __restrict__ deg, int E)
{
    int e = blockIdx.x * blockDim.x + threadIdx.x;
    if (e < E) atomicAdd(&deg[dst[e]], 1);
}

__global__ void scan1_kernel(const int* __restrict__ deg, int* __restrict__ incl,
                             int* __restrict__ bsum, int N)
{
    __shared__ int sm[256];
    int i = blockIdx.x * 256 + threadIdx.x;
    int v = (i < N) ? deg[i] : 0;
    sm[threadIdx.x] = v;
    __syncthreads();
    for (int off = 1; off < 256; off <<= 1) {
        int t = (threadIdx.x >= off) ? sm[threadIdx.x - off] : 0;
        __syncthreads();
        sm[threadIdx.x] += t;
        __syncthreads();
    }
    if (i < N) incl[i] = sm[threadIdx.x];
    if (threadIdx.x == 255) bsum[blockIdx.x] = sm[255];
}

__global__ void scan2_kernel(int* __restrict__ bsum, int nb)
{
    __shared__ int sm[256];
    int v = (threadIdx.x < nb) ? bsum[threadIdx.x] : 0;
    sm[threadIdx.x] = v;
    __syncthreads();
    for (int off = 1; off < 256; off <<= 1) {
        int t = (threadIdx.x >= off) ? sm[threadIdx.x - off] : 0;
        __syncthreads();
        sm[threadIdx.x] += t;
        __syncthreads();
    }
    if (threadIdx.x < nb) bsum[threadIdx.x] = sm[threadIdx.x];
}

__global__ void scan3_kernel(const int* __restrict__ incl, const int* __restrict__ bsum,
                             int* __restrict__ row_ptr, int N)
{
    int i = blockIdx.x * 256 + threadIdx.x;
    if (i < N) {
        int off = (blockIdx.x > 0) ? bsum[blockIdx.x - 1] : 0;
        row_ptr[i + 1] = incl[i] + off;
    }
    if (i == 0) row_ptr[0] = 0;
}

__global__ void scatter_kernel(const int* __restrict__ src, const int* __restrict__ dst,
                               const int* __restrict__ row_ptr, int* __restrict__ cursor,
                               int* __restrict__ csr_src, int E)
{
    int e = blockIdx.x * blockDim.x + threadIdx.x;
    if (e >= E) return;
    int t = dst[e];
    int pos = atomicAdd(&cursor[t], 1);
    csr_src[row_ptr[t] + pos] = src[e];
}

// ---------------------------------------------------------------------------
// Fused: edge-softmax + aggregate (bf16 z) + conv bias + PReLU + LN1 + LN2.
// One wave per dst node; edge loop unrolled x4 for memory-level parallelism
// (independent csr->el->z load chains per unrolled edge).
// ---------------------------------------------------------------------------
__global__ __launch_bounds__(256) void gat_agg_ln_kernel(
    const int* __restrict__ row_ptr, const int* __restrict__ csr_src,
    const short* __restrict__ z, const float* __restrict__ el,
    const float* __restrict__ er, const float* __restrict__ cb,
    const float* __restrict__ a_conv,
    const float* __restrict__ scale, const float* __restrict__ bias,
    float* __restrict__ h_out, short* __restrict__ hn_out, int N)
{
    int wave = threadIdx.x >> 6, lane = threadIdx.x & 63;
    int t = blockIdx.x * 4 + wave;
    if (t >= N) return;
    int h = lane >> 3;
    int c0 = 2 * lane, c1 = c0 + 1;
    float er_t = er[t * NH + h];
    int e0 = row_ptr[t], e1 = row_ptr[t + 1];
    float acc0 = 0.0f, acc1 = 0.0f, den = 0.0f;
    const unsigned* zw = (const unsigned*)z;

    int e = e0;
    for (; e + 4 <= e1; e += 4) {
        int s0 = csr_src[e], s1 = csr_src[e + 1], s2 = csr_src[e + 2], s3 = csr_src[e + 3];
        float x0 = el[s0 * NH + h] + er_t;
        float x1 = el[s1 * NH + h] + er_t;
        float x2 = el[s2 * NH + h] + er_t;
        float x3 = el[s3 * NH + h] + er_t;
        unsigned u0 = zw[(size_t)s0 * 64 + lane];
        unsigned u1 = zw[(size_t)s1 * 64 + lane];
        unsigned u2 = zw[(size_t)s2 * 64 + lane];
        unsigned u3 = zw[(size_t)s3 * 64 + lane];
        x0 = (x0 >= 0.0f) ? x0 : 0.2f * x0;
        x1 = (x1 >= 0.0f) ? x1 : 0.2f * x1;
        x2 = (x2 >= 0.0f) ? x2 : 0.2f * x2;
        x3 = (x3 >= 0.0f) ? x3 : 0.2f * x3;
        float w0 = __expf(x0), w1 = __expf(x1), w2 = __expf(x2), w3 = __expf(x3);
        den += (w0 + w1) + (w2 + w3);
        acc0 = fmaf(w0, bf2f((unsigned short)(u0 & 0xffff)), acc0);
        acc1 = fmaf(w0, bf2f((unsigned short)(u0 >> 16)),   acc1);
        acc0 = fmaf(w1, bf2f((unsigned short)(u1 & 0xffff)), acc0);
        acc1 = fmaf(w1, bf2f((unsigned short)(u1 >> 16)),   acc1);
        acc0 = fmaf(w2, bf2f((unsigned short)(u2 & 0xffff)), acc0);
        acc1 = fmaf(w2, bf2f((unsigned short)(u2 >> 16)),   acc1);
        acc0 = fmaf(w3, bf2f((unsigned short)(u3 & 0xffff)), acc0);
        acc1 = fmaf(w3, bf2f((unsigned short)(u3 >> 16)),   acc1);
    }
    for (; e < e1; ++e) {
        int s = csr_src[e];
        float v = el[s * NH + h] + er_t;
        v = (v >= 0.0f) ? v : 0.2f * v;
        float w = __expf(v);
        den += w;
        unsigned u = zw[(size_t)s * 64 + lane];
        acc0 = fmaf(w, bf2f((unsigned short)(u & 0xffff)), acc0);
        acc1 = fmaf(w, bf2f((unsigned short)(u >> 16)), acc1);
    }

    float a = *a_conv;
    float inv = 1.0f / fmaxf(den, 1e-9f);
    float o0 = acc0 * inv + cb[c0];
    float o1 = acc1 * inv + cb[c1];
    o0 = (o0 >= 0.0f) ? o0 : a * o0;
    o1 = (o1 >= 0.0f) ? o1 : a * o1;

    float sc0 = scale[c0], sc1 = scale[c1];
    float bi0 = bias[c0], bi1 = bias[c1];

    // LN1
    float s1 = o0 + o1, ss = o0 * o0 + o1 * o1;
#pragma unroll
    for (int off = 32; off > 0; off >>= 1) {
        s1 += __shfl_xor(s1, off, 64);
        ss += __shfl_xor(ss, off, 64);
    }
    float mean = s1 * (1.0f / 128.0f);
    float var = ss * (1.0f / 128.0f) - mean * mean;
    float rstd = rsqrtf(var + 1e-5f);
    float h0 = (o0 - mean) * rstd * sc0 + bi0;
    float h1 = (o1 - mean) * rstd * sc1 + bi1;
    ((float2*)h_out)[(size_t)t * 64 + lane] = make_float2(h0, h1);

    // LN2
    s1 = h0 + h1; ss = h0 * h0 + h1 * h1;
#pragma unroll
    for (int off = 32; off > 0; off >>= 1) {
        s1 += __shfl_xor(s1, off, 64);
        ss += __shfl_xor(ss, off, 64);
    }
    mean = s1 * (1.0f / 128.0f);
    var = ss * (1.0f / 128.0f) - mean * mean;
    rstd = rsqrtf(var + 1e-5f);
    unsigned lo = (unsigned short)f2bf((h0 - mean) * rstd * sc0 + bi0);
    unsigned hi = (unsigned short)f2bf((h1 - mean) * rstd * sc1 + bi1);
    ((unsigned*)hn_out)[(size_t)t * 64 + lane] = lo | (hi << 16);
}

extern "C" void kernel_launch(void* const* d_in, const int* in_sizes, int n_in,
                              void* d_out, int out_size, void* d_ws, size_t ws_size,
                              hipStream_t stream)
{
    const float* in_feats = (const float*)d_in[0];
    const int*   src      = (const int*)d_in[1];
    const int*   dst      = (const int*)d_in[2];
    const float* W        = (const float*)d_in[3];
    const float* attn_l   = (const float*)d_in[4];
    const float* attn_r   = (const float*)d_in[5];
    const float* convb    = (const float*)d_in[6];
    const float* a_conv   = (const float*)d_in[7];
    const float* ln_scale = (const float*)d_in[8];
    const float* ln_bias  = (const float*)d_in[9];
    const float* W1       = (const float*)d_in[10];
    const float* b1       = (const float*)d_in[11];
    const float* W2       = (const float*)d_in[12];
    const float* b2       = (const float*)d_in[13];
    const float* a_ff     = (const float*)d_in[14];
    float* out = (float*)d_out;

    const int N = in_sizes[0] / DM;
    const int E = in_sizes[1];
    const int L = in_sizes[7];

    char* wsb = (char*)d_ws;
    size_t off = 0;
    auto alloc = [&](size_t bytes) { char* p = wsb + off; off += (bytes + 255) & ~(size_t)255; return p; };

    short* z_bf  = (short*)alloc((size_t)N * DM * sizeof(short));
    float* el    = (float*)alloc((size_t)N * NH * sizeof(float));
    float* er    = (float*)alloc((size_t)N * NH * sizeof(float));
    float* hbuf  = (float*)alloc((size_t)N * DM * sizeof(float));   // h (LN1 out, residual)
    short* hn_bf = (short*)alloc((size_t)N * DM * sizeof(short));
    short* ffh_bf= (short*)alloc((size_t)N * DFF * sizeof(short));
    short* x_bf  = (short*)alloc((size_t)N * DM * sizeof(short));
    short* Wt    = (short*)alloc((size_t)L * DM * DM * sizeof(short));
    short* W1t   = (short*)alloc((size_t)L * DFF * DM * sizeof(short));
    short* W2t   = (short*)alloc((size_t)L * DM * DFF * sizeof(short));
    int* deg     = (int*)alloc((size_t)N * sizeof(int));
    int* incl    = (int*)alloc((size_t)N * sizeof(int));
    int* bsum    = (int*)alloc(256 * sizeof(int));
    int* row_ptr = (int*)alloc((size_t)(N + 1) * sizeof(int));
    int* cursor  = (int*)alloc((size_t)N * sizeof(int));
    int* csr_src = (int*)alloc((size_t)E * sizeof(int));

    const int gM128 = (N + 127) / 128;
    const int nbScan = (N + 255) / 256;

    // ---- CSR by dst ----
    hipMemsetAsync(deg, 0, (size_t)N * sizeof(int), stream);
    hipMemsetAsync(cursor, 0, (size_t)N * sizeof(int), stream);
    hist_kernel<<<(E + 255) / 256, 256, 0, stream>>>(dst, deg, E);
    scan1_kernel<<<nbScan, 256, 0, stream>>>(deg, incl, bsum, N);
    scan2_kernel<<<1, 256, 0, stream>>>(bsum, nbScan);
    scan3_kernel<<<nbScan, 256, 0, stream>>>(incl, bsum, row_ptr, N);
    scatter_kernel<<<(E + 255) / 256, 256, 0, stream>>>(src, dst, row_ptr, cursor, csr_src, E);

    // ---- weight convert+transpose (all layers per launch), input convert ----
    wt_conv_kernel<<<(L * DM * DM + 255) / 256, 256, 0, stream>>>(W, Wt, DM, DM, L);
    wt_conv_kernel<<<(L * DM * DFF + 255) / 256, 256, 0, stream>>>(W1, W1t, DM, DFF, L);
    wt_conv_kernel<<<(L * DFF * DM + 255) / 256, 256, 0, stream>>>(W2, W2t, DFF, DM, L);
    f2bf_kernel<<<(N * DM + 255) / 256, 256, 0, stream>>>(in_feats, x_bf, N * DM);

    for (int l = 0; l < L; ++l) {
        float* xo = out + (size_t)l * N * DM;

        // z_bf = bf16(x_bf @ W[l])
        gemm_direct<DM><<<dim3(1, gM128), 256, 0, stream>>>(
            x_bf, Wt + (size_t)l * DM * DM, N, DM,
            nullptr, nullptr, nullptr, nullptr, z_bf);

        el_er_kernel<<<(N * NH + 255) / 256, 256, 0, stream>>>(
            z_bf, attn_l + (size_t)l * NH * HD, attn_r + (size_t)l * NH * HD, el, er, N);

        // aggregate + bias + prelu + LN1 (-> hbuf fp32) + LN2 (-> hn_bf)
        gat_agg_ln_kernel<<<(N + 3) / 4, 256, 0, stream>>>(
            row_ptr, csr_src, z_bf, el, er, convb + (size_t)l * DM, a_conv + l,
            ln_scale + (size_t)l * DM, ln_bias + (size_t)l * DM, hbuf, hn_bf, N);

        // ffh_bf = bf16(prelu(hn @ W1 + b1, a_ff))
        gemm_direct<DM><<<dim3(DFF / 128, gM128), 256, 0, stream>>>(
            hn_bf, W1t + (size_t)l * DFF * DM, N, DFF,
            b1 + (size_t)l * DFF, a_ff + l, nullptr, nullptr, ffh_bf);

        // xo = ffh @ W2 + b2 + h ; x_bf = bf16(xo)
        gemm_direct<DFF><<<dim3(1, gM128), 256, 0, stream>>>(
            ffh_bf, W2t + (size_t)l * DM * DFF, N, DM,
            b2 + (size_t)l * DM, nullptr, hbuf, xo, x_bf);
    }
}

// Round 6
// 577.075 us; speedup vs baseline: 3.5238x; 1.4183x over previous
//
#include <hip/hip_runtime.h>

#define DM 128
#define NH 8
#define DFF 512
#define MT 32           // ff_fused M-tile rows
#define FS 520          // ffh LDS row stride in shorts (512 + 8 pad -> bank shift 4)
#define XS 136          // x-tile LDS row stride in shorts (128 + 8 pad)

typedef __attribute__((ext_vector_type(8))) short bf16x8;
typedef __attribute__((ext_vector_type(4))) float f32x4;

__device__ __forceinline__ short f2bf(float f) {
    union { float f; unsigned u; } v; v.f = f;
    unsigned r = v.u + 0x7fffu + ((v.u >> 16) & 1u);   // RNE
    return (short)(r >> 16);
}
__device__ __forceinline__ float bf2f(unsigned short b) {
    union { unsigned u; float f; } v; v.u = ((unsigned)b) << 16; return v.f;
}

// ---------------------------------------------------------------------------
// LDS-free bf16 MFMA GEMM (layer-0 z projection only). C = A[M,K] @ BT[Nc,K]^T.
// ---------------------------------------------------------------------------
template<int K>
__global__ __launch_bounds__(256) void gemm_direct(
    const short* __restrict__ A, const short* __restrict__ BT,
    int M, int Nc, short* __restrict__ Cbf)
{
    constexpr int nK = K / 32;
    const int tid = threadIdx.x;
    const int wave = tid >> 6, lane = tid & 63;
    const int wm = wave >> 1, wn = wave & 1;
    const int bm = blockIdx.y * 128, bn = blockIdx.x * 128;
    const int fr = lane & 15;
    const int fk = (lane >> 4) << 3;

    const short* Ab[4];
    const short* Bb[4];
#pragma unroll
    for (int i = 0; i < 4; ++i) {
        int row = bm + wm * 64 + i * 16 + fr;
        row = (row < M) ? row : (M - 1);
        Ab[i] = A + (size_t)row * K + fk;
    }
#pragma unroll
    for (int j = 0; j < 4; ++j) {
        int col = bn + wn * 64 + j * 16 + fr;
        Bb[j] = BT + (size_t)col * K + fk;
    }

    f32x4 acc[4][4];
#pragma unroll
    for (int i = 0; i < 4; ++i)
#pragma unroll
        for (int j = 0; j < 4; ++j) acc[i][j] = (f32x4)0.0f;

#pragma unroll
    for (int ks = 0; ks < nK; ++ks) {
        bf16x8 af[4], bfr[4];
#pragma unroll
        for (int i = 0; i < 4; ++i) {
            af[i]  = *(const bf16x8*)(Ab[i] + ks * 32);
            bfr[i] = *(const bf16x8*)(Bb[i] + ks * 32);
        }
#pragma unroll
        for (int i = 0; i < 4; ++i)
#pragma unroll
            for (int j = 0; j < 4; ++j)
                acc[i][j] = __builtin_amdgcn_mfma_f32_16x16x32_bf16(
                    af[i], bfr[j], acc[i][j], 0, 0, 0);
    }

    const int row0 = bm + wm * 64;
    const int col0 = bn + wn * 64;
    const int lr = (lane >> 4) * 4;
    const int lc = lane & 15;
#pragma unroll
    for (int i = 0; i < 4; ++i)
#pragma unroll
        for (int r = 0; r < 4; ++r) {
            int row = row0 + i * 16 + lr + r;
            if (row >= M) continue;
#pragma unroll
            for (int j = 0; j < 4; ++j) {
                int col = col0 + j * 16 + lc;
                Cbf[(size_t)row * Nc + col] = f2bf(acc[i][j][r]);
            }
        }
}

// ---------------------------------------------------------------------------
// Fused FF + next-layer projection, one block per 32-row tile:
//  G1: ffh = prelu(hn @ W1 + b1)           (wave -> 128 of 512 cols) -> LDS
//  G2: xo  = ffh @ W2 + b2 + h  (fp32 out) (wave -> 32 of 128 cols)  -> LDS
//  G3: z'  = xo @ Wnext (bf16 out)         (wave -> 32 of 128 cols)
// Weights stream from L2 (288 KB total, shared by all blocks).
// ---------------------------------------------------------------------------
__global__ __launch_bounds__(256) void ff_fused(
    const short* __restrict__ hn, const short* __restrict__ W1t,
    const short* __restrict__ W2t, const short* __restrict__ h_bf,
    const float* __restrict__ b1, const float* __restrict__ b2,
    const float* __restrict__ a_ff, float* __restrict__ xo,
    const short* __restrict__ Wnt, short* __restrict__ z_next, int M)
{
    __shared__ short sF[MT * FS];   // 33,280 B ffh tile (padded)
    __shared__ short sX[MT * XS];   //  8,704 B x tile (padded)

    const int tid = threadIdx.x;
    const int wave = tid >> 6, lane = tid & 63;
    const int m0 = blockIdx.x * MT;
    const int fr  = lane & 15;
    const int fk8 = (lane >> 4) << 3;   // 0,8,16,24 (k elems)
    const int lr4 = (lane >> 4) << 2;   // 0,4,8,12 (C-layout row base)
    const int lc  = lane & 15;

    // ---------------- G1 ----------------
    bf16x8 afr[2][4];
#pragma unroll
    for (int rg = 0; rg < 2; ++rg)
#pragma unroll
        for (int ks = 0; ks < 4; ++ks) {
            int row = m0 + rg * 16 + fr;
            row = (row < M) ? row : (M - 1);
            afr[rg][ks] = *(const bf16x8*)(hn + (size_t)row * DM + ks * 32 + fk8);
        }

    f32x4 acc1[2][8];
#pragma unroll
    for (int rg = 0; rg < 2; ++rg)
#pragma unroll
        for (int cg = 0; cg < 8; ++cg) acc1[rg][cg] = (f32x4)0.0f;

    const short* w1base = W1t + (size_t)(wave * 128 + fr) * DM + fk8;
#pragma unroll
    for (int ks = 0; ks < 4; ++ks) {
        bf16x8 bfr[8];
#pragma unroll
        for (int cg = 0; cg < 8; ++cg)
            bfr[cg] = *(const bf16x8*)(w1base + (size_t)cg * 16 * DM + ks * 32);
#pragma unroll
        for (int rg = 0; rg < 2; ++rg)
#pragma unroll
            for (int cg = 0; cg < 8; ++cg)
                acc1[rg][cg] = __builtin_amdgcn_mfma_f32_16x16x32_bf16(
                    afr[rg][ks], bfr[cg], acc1[rg][cg], 0, 0, 0);
    }

    float aff = *a_ff;
#pragma unroll
    for (int rg = 0; rg < 2; ++rg)
#pragma unroll
        for (int cg = 0; cg < 8; ++cg) {
            int colL = wave * 128 + cg * 16 + lc;
            float bb = b1[colL];
#pragma unroll
            for (int r = 0; r < 4; ++r) {
                int rowL = rg * 16 + lr4 + r;
                float v = acc1[rg][cg][r] + bb;
                v = (v >= 0.0f) ? v : aff * v;
                sF[rowL * FS + colL] = f2bf(v);
            }
        }
    __syncthreads();

    // ---------------- G2 ----------------
    f32x4 acc2[2][2];
#pragma unroll
    for (int rg = 0; rg < 2; ++rg)
#pragma unroll
        for (int cg = 0; cg < 2; ++cg) acc2[rg][cg] = (f32x4)0.0f;

    const short* w2base = W2t + (size_t)(wave * 32 + fr) * DFF + fk8;
#pragma unroll
    for (int ks = 0; ks < 16; ++ks) {
        bf16x8 a2[2], b2f[2];
#pragma unroll
        for (int rg = 0; rg < 2; ++rg)
            a2[rg] = *(const bf16x8*)(sF + (rg * 16 + fr) * FS + ks * 32 + fk8);
#pragma unroll
        for (int cg = 0; cg < 2; ++cg)
            b2f[cg] = *(const bf16x8*)(w2base + (size_t)cg * 16 * DFF + ks * 32);
#pragma unroll
        for (int rg = 0; rg < 2; ++rg)
#pragma unroll
            for (int cg = 0; cg < 2; ++cg)
                acc2[rg][cg] = __builtin_amdgcn_mfma_f32_16x16x32_bf16(
                    a2[rg], b2f[cg], acc2[rg][cg], 0, 0, 0);
    }

    const bool has_next = (Wnt != nullptr);
#pragma unroll
    for (int rg = 0; rg < 2; ++rg)
#pragma unroll
        for (int cg = 0; cg < 2; ++cg) {
            int colL = wave * 32 + cg * 16 + lc;
            float bb = b2[colL];
#pragma unroll
            for (int r = 0; r < 4; ++r) {
                int rowL = rg * 16 + lr4 + r;
                int row = m0 + rowL;
                int rc = (row < M) ? row : (M - 1);
                float v = acc2[rg][cg][r] + bb
                        + bf2f((unsigned short)h_bf[(size_t)rc * DM + colL]);
                if (row < M) xo[(size_t)row * DM + colL] = v;
                if (has_next) sX[rowL * XS + colL] = f2bf(v);
            }
        }
    if (!has_next) return;
    __syncthreads();

    // ---------------- G3 ----------------
    f32x4 acc3[2][2];
#pragma unroll
    for (int rg = 0; rg < 2; ++rg)
#pragma unroll
        for (int cg = 0; cg < 2; ++cg) acc3[rg][cg] = (f32x4)0.0f;

    const short* wnb = Wnt + (size_t)(wave * 32 + fr) * DM + fk8;
#pragma unroll
    for (int ks = 0; ks < 4; ++ks) {
        bf16x8 a3[2], b3[2];
#pragma unroll
        for (int rg = 0; rg < 2; ++rg)
            a3[rg] = *(const bf16x8*)(sX + (rg * 16 + fr) * XS + ks * 32 + fk8);
#pragma unroll
        for (int cg = 0; cg < 2; ++cg)
            b3[cg] = *(const bf16x8*)(wnb + (size_t)cg * 16 * DM + ks * 32);
#pragma unroll
        for (int rg = 0; rg < 2; ++rg)
#pragma unroll
            for (int cg = 0; cg < 2; ++cg)
                acc3[rg][cg] = __builtin_amdgcn_mfma_f32_16x16x32_bf16(
                    a3[rg], b3[cg], acc3[rg][cg], 0, 0, 0);
    }
#pragma unroll
    for (int rg = 0; rg < 2; ++rg)
#pragma unroll
        for (int cg = 0; cg < 2; ++cg) {
            int colL = wave * 32 + cg * 16 + lc;
#pragma unroll
            for (int r = 0; r < 4; ++r) {
                int row = m0 + rg * 16 + lr4 + r;
                if (row < M)
                    z_next[(size_t)row * DM + colL] = f2bf(acc3[rg][cg][r]);
            }
        }
}

// transpose + fp32->bf16 for all L layers: out[l][c][r] = bf16(in[l][r][c])
__global__ void wt_conv_kernel(const float* __restrict__ in, short* __restrict__ out,
                               int R, int C, int nL)
{
    int idx = blockIdx.x * blockDim.x + threadIdx.x;
    if (idx >= nL * R * C) return;
    int l = idx / (R * C);
    int rem = idx - l * (R * C);
    int r = rem / C, c = rem - r * C;
    out[(size_t)l * R * C + (size_t)c * R + r] = f2bf(in[idx]);
}

__global__ void f2bf_kernel(const float* __restrict__ in, short* __restrict__ out, int n)
{
    int idx = blockIdx.x * blockDim.x + threadIdx.x;
    if (idx < n) out[idx] = f2bf(in[idx]);
}

// el/er from bf16 z
__global__ void el_er_kernel(const short* __restrict__ z,
                             const float* __restrict__ al,
                             const float* __restrict__ ar,
                             float* __restrict__ el, float* __restrict__ er, int N)
{
    int idx = blockIdx.x * blockDim.x + threadIdx.x;
    if (idx >= N * NH) return;
    int n = idx >> 3, h = idx & 7;
    const unsigned* zp = (const unsigned*)(z + (size_t)n * DM + h * 16);
    const float* alp = al + h * 16;
    const float* arp = ar + h * 16;
    float sl = 0.0f, sr = 0.0f;
#pragma unroll
    for (int d2 = 0; d2 < 8; ++d2) {
        unsigned u = zp[d2];
        float z0 = bf2f((unsigned short)(u & 0xffff));
        float z1 = bf2f((unsigned short)(u >> 16));
        sl = fmaf(z0, alp[2 * d2], sl);     sl = fmaf(z1, alp[2 * d2 + 1], sl);
        sr = fmaf(z0, arp[2 * d2], sr);     sr = fmaf(z1, arp[2 * d2 + 1], sr);
    }
    el[idx] = sl;
    er[idx] = sr;
}

// ---------------- CSR build ----------------
__global__ void hist_kernel(const int* __restrict__ dst, int* __restrict__ deg, int E)
{
    int e = blockIdx.x * blockDim.x + threadIdx.x;
    if (e < E) atomicAdd(&deg[dst[e]], 1);
}

__global__ void scan1_kernel(const int* __restrict__ deg, int* __restrict__ incl,
                             int* __restrict__ bsum, int N)
{
    __shared__ int sm[256];
    int i = blockIdx.x * 256 + threadIdx.x;
    int v = (i < N) ? deg[i] : 0;
    sm[threadIdx.x] = v;
    __syncthreads();
    for (int off = 1; off < 256; off <<= 1) {
        int t = (threadIdx.x >= off) ? sm[threadIdx.x - off] : 0;
        __syncthreads();
        sm[threadIdx.x] += t;
        __syncthreads();
    }
    if (i < N) incl[i] = sm[threadIdx.x];
    if (threadIdx.x == 255) bsum[blockIdx.x] = sm[255];
}

__global__ void scan2_kernel(int* __restrict__ bsum, int nb)
{
    __shared__ int sm[256];
    int v = (threadIdx.x < nb) ? bsum[threadIdx.x] : 0;
    sm[threadIdx.x] = v;
    __syncthreads();
    for (int off = 1; off < 256; off <<= 1) {
        int t = (threadIdx.x >= off) ? sm[threadIdx.x - off] : 0;
        __syncthreads();
        sm[threadIdx.x] += t;
        __syncthreads();
    }
    if (threadIdx.x < nb) bsum[threadIdx.x] = sm[threadIdx.x];
}

__global__ void scan3_kernel(const int* __restrict__ incl, const int* __restrict__ bsum,
                             int* __restrict__ row_ptr, int N)
{
    int i = blockIdx.x * 256 + threadIdx.x;
    if (i < N) {
        int off = (blockIdx.x > 0) ? bsum[blockIdx.x - 1] : 0;
        row_ptr[i + 1] = incl[i] + off;
    }
    if (i == 0) row_ptr[0] = 0;
}

__global__ void scatter_kernel(const int* __restrict__ src, const int* __restrict__ dst,
                               const int* __restrict__ row_ptr, int* __restrict__ cursor,
                               int* __restrict__ csr_src, int E)
{
    int e = blockIdx.x * blockDim.x + threadIdx.x;
    if (e >= E) return;
    int t = dst[e];
    int pos = atomicAdd(&cursor[t], 1);
    csr_src[row_ptr[t] + pos] = src[e];
}

// ---------------------------------------------------------------------------
// Fused: edge-softmax + aggregate (bf16 z) + conv bias + PReLU + LN1 + LN2.
// One wave per dst node; unroll-8 edge groups for memory-level parallelism.
// Writes h (bf16 residual) and hn (bf16 FF input).
// ---------------------------------------------------------------------------
__global__ __launch_bounds__(256) void gat_agg_ln_kernel(
    const int* __restrict__ row_ptr, const int* __restrict__ csr_src,
    const short* __restrict__ z, const float* __restrict__ el,
    const float* __restrict__ er, const float* __restrict__ cb,
    const float* __restrict__ a_conv,
    const float* __restrict__ scale, const float* __restrict__ bias,
    short* __restrict__ h_out, short* __restrict__ hn_out, int N)
{
    int wave = threadIdx.x >> 6, lane = threadIdx.x & 63;
    int t = blockIdx.x * 4 + wave;
    if (t >= N) return;
    int h = lane >> 3;
    int c0 = 2 * lane, c1 = c0 + 1;
    float er_t = er[t * NH + h];
    int e0 = row_ptr[t], e1 = row_ptr[t + 1];
    float acc0 = 0.0f, acc1 = 0.0f, den = 0.0f;
    const unsigned* zw = (const unsigned*)z;

    int e = e0;
    for (; e + 8 <= e1; e += 8) {
        int s[8];
#pragma unroll
        for (int k = 0; k < 8; ++k) s[k] = csr_src[e + k];
        float x[8]; unsigned u[8];
#pragma unroll
        for (int k = 0; k < 8; ++k) x[k] = el[s[k] * NH + h];
#pragma unroll
        for (int k = 0; k < 8; ++k) u[k] = zw[(size_t)s[k] * 64 + lane];
#pragma unroll
        for (int k = 0; k < 8; ++k) {
            float v = x[k] + er_t;
            v = (v >= 0.0f) ? v : 0.2f * v;
            float w = __expf(v);
            den += w;
            acc0 = fmaf(w, bf2f((unsigned short)(u[k] & 0xffff)), acc0);
            acc1 = fmaf(w, bf2f((unsigned short)(u[k] >> 16)),   acc1);
        }
    }
    for (; e + 4 <= e1; e += 4) {
        int s[4];
#pragma unroll
        for (int k = 0; k < 4; ++k) s[k] = csr_src[e + k];
        float x[4]; unsigned u[4];
#pragma unroll
        for (int k = 0; k < 4; ++k) x[k] = el[s[k] * NH + h];
#pragma unroll
        for (int k = 0; k < 4; ++k) u[k] = zw[(size_t)s[k] * 64 + lane];
#pragma unroll
        for (int k = 0; k < 4; ++k) {
            float v = x[k] + er_t;
            v = (v >= 0.0f) ? v : 0.2f * v;
            float w = __expf(v);
            den += w;
            acc0 = fmaf(w, bf2f((unsigned short)(u[k] & 0xffff)), acc0);
            acc1 = fmaf(w, bf2f((unsigned short)(u[k] >> 16)),   acc1);
        }
    }
    for (; e < e1; ++e) {
        int s = csr_src[e];
        float v = el[s * NH + h] + er_t;
        v = (v >= 0.0f) ? v : 0.2f * v;
        float w = __expf(v);
        den += w;
        unsigned u = zw[(size_t)s * 64 + lane];
        acc0 = fmaf(w, bf2f((unsigned short)(u & 0xffff)), acc0);
        acc1 = fmaf(w, bf2f((unsigned short)(u >> 16)), acc1);
    }

    float a = *a_conv;
    float inv = 1.0f / fmaxf(den, 1e-9f);
    float o0 = acc0 * inv + cb[c0];
    float o1 = acc1 * inv + cb[c1];
    o0 = (o0 >= 0.0f) ? o0 : a * o0;
    o1 = (o1 >= 0.0f) ? o1 : a * o1;

    float sc0 = scale[c0], sc1 = scale[c1];
    float bi0 = bias[c0], bi1 = bias[c1];

    // LN1
    float s1 = o0 + o1, ss = o0 * o0 + o1 * o1;
#pragma unroll
    for (int off = 32; off > 0; off >>= 1) {
        s1 += __shfl_xor(s1, off, 64);
        ss += __shfl_xor(ss, off, 64);
    }
    float mean = s1 * (1.0f / 128.0f);
    float var = ss * (1.0f / 128.0f) - mean * mean;
    float rstd = rsqrtf(var + 1e-5f);
    float h0 = (o0 - mean) * rstd * sc0 + bi0;
    float h1 = (o1 - mean) * rstd * sc1 + bi1;
    unsigned hlo = (unsigned short)f2bf(h0);
    unsigned hhi = (unsigned short)f2bf(h1);
    ((unsigned*)h_out)[(size_t)t * 64 + lane] = hlo | (hhi << 16);

    // LN2
    s1 = h0 + h1; ss = h0 * h0 + h1 * h1;
#pragma unroll
    for (int off = 32; off > 0; off >>= 1) {
        s1 += __shfl_xor(s1, off, 64);
        ss += __shfl_xor(ss, off, 64);
    }
    mean = s1 * (1.0f / 128.0f);
    var = ss * (1.0f / 128.0f) - mean * mean;
    rstd = rsqrtf(var + 1e-5f);
    unsigned lo = (unsigned short)f2bf((h0 - mean) * rstd * sc0 + bi0);
    unsigned hi = (unsigned short)f2bf((h1 - mean) * rstd * sc1 + bi1);
    ((unsigned*)hn_out)[(size_t)t * 64 + lane] = lo | (hi << 16);
}

extern "C" void kernel_launch(void* const* d_in, const int* in_sizes, int n_in,
                              void* d_out, int out_size, void* d_ws, size_t ws_size,
                              hipStream_t stream)
{
    const float* in_feats = (const float*)d_in[0];
    const int*   src      = (const int*)d_in[1];
    const int*   dst      = (const int*)d_in[2];
    const float* W        = (const float*)d_in[3];
    const float* attn_l   = (const float*)d_in[4];
    const float* attn_r   = (const float*)d_in[5];
    const float* convb    = (const float*)d_in[6];
    const float* a_conv   = (const float*)d_in[7];
    const float* ln_scale = (const float*)d_in[8];
    const float* ln_bias  = (const float*)d_in[9];
    const float* W1       = (const float*)d_in[10];
    const float* b1       = (const float*)d_in[11];
    const float* W2       = (const float*)d_in[12];
    const float* b2       = (const float*)d_in[13];
    const float* a_ff     = (const float*)d_in[14];
    float* out = (float*)d_out;

    const int N = in_sizes[0] / DM;
    const int E = in_sizes[1];
    const int L = in_sizes[7];

    char* wsb = (char*)d_ws;
    size_t off = 0;
    auto alloc = [&](size_t bytes) { char* p = wsb + off; off += (bytes + 255) & ~(size_t)255; return p; };

    short* z_bf  = (short*)alloc((size_t)N * DM * sizeof(short));
    short* h_bf  = (short*)alloc((size_t)N * DM * sizeof(short));
    short* hn_bf = (short*)alloc((size_t)N * DM * sizeof(short));
    short* x_bf  = (short*)alloc((size_t)N * DM * sizeof(short));
    float* el    = (float*)alloc((size_t)N * NH * sizeof(float));
    float* er    = (float*)alloc((size_t)N * NH * sizeof(float));
    short* Wt    = (short*)alloc((size_t)L * DM * DM * sizeof(short));
    short* W1t   = (short*)alloc((size_t)L * DFF * DM * sizeof(short));
    short* W2t   = (short*)alloc((size_t)L * DM * DFF * sizeof(short));
    int* deg     = (int*)alloc((size_t)N * sizeof(int));
    int* incl    = (int*)alloc((size_t)N * sizeof(int));
    int* bsum    = (int*)alloc(256 * sizeof(int));
    int* row_ptr = (int*)alloc((size_t)(N + 1) * sizeof(int));
    int* cursor  = (int*)alloc((size_t)N * sizeof(int));
    int* csr_src = (int*)alloc((size_t)E * sizeof(int));

    const int gM128 = (N + 127) / 128;
    const int gMT = (N + MT - 1) / MT;
    const int nbScan = (N + 255) / 256;

    // ---- CSR by dst ----
    hipMemsetAsync(deg, 0, (size_t)N * sizeof(int), stream);
    hipMemsetAsync(cursor, 0, (size_t)N * sizeof(int), stream);
    hist_kernel<<<(E + 255) / 256, 256, 0, stream>>>(dst, deg, E);
    scan1_kernel<<<nbScan, 256, 0, stream>>>(deg, incl, bsum, N);
    scan2_kernel<<<1, 256, 0, stream>>>(bsum, nbScan);
    scan3_kernel<<<nbScan, 256, 0, stream>>>(incl, bsum, row_ptr, N);
    scatter_kernel<<<(E + 255) / 256, 256, 0, stream>>>(src, dst, row_ptr, cursor, csr_src, E);

    // ---- weight convert+transpose, input convert ----
    wt_conv_kernel<<<(L * DM * DM + 255) / 256, 256, 0, stream>>>(W, Wt, DM, DM, L);
    wt_conv_kernel<<<(L * DM * DFF + 255) / 256, 256, 0, stream>>>(W1, W1t, DM, DFF, L);
    wt_conv_kernel<<<(L * DFF * DM + 255) / 256, 256, 0, stream>>>(W2, W2t, DFF, DM, L);
    f2bf_kernel<<<(N * DM + 255) / 256, 256, 0, stream>>>(in_feats, x_bf, N * DM);

    // layer-0 z projection
    gemm_direct<DM><<<dim3(1, gM128), 256, 0, stream>>>(
        x_bf, Wt, N, DM, z_bf);

    for (int l = 0; l < L; ++l) {
        float* xo = out + (size_t)l * N * DM;
        const short* Wnt = (l + 1 < L) ? (Wt + (size_t)(l + 1) * DM * DM) : nullptr;

        el_er_kernel<<<(N * NH + 255) / 256, 256, 0, stream>>>(
            z_bf, attn_l + (size_t)l * NH * 16, attn_r + (size_t)l * NH * 16, el, er, N);

        gat_agg_ln_kernel<<<(N + 3) / 4, 256, 0, stream>>>(
            row_ptr, csr_src, z_bf, el, er, convb + (size_t)l * DM, a_conv + l,
            ln_scale + (size_t)l * DM, ln_bias + (size_t)l * DM, h_bf, hn_bf, N);

        // xo = prelu(hn@W1+b1)@W2 + b2 + h ; z_bf = xo @ W[l+1] (if any)
        ff_fused<<<gMT, 256, 0, stream>>>(
            hn_bf, W1t + (size_t)l * DFF * DM, W2t + (size_t)l * DM * DFF,
            h_bf, b1 + (size_t)l * DFF, b2 + (size_t)l * DM, a_ff + l,
            xo, Wnt, z_bf, N);
    }
}